// Round 1
// baseline (1074.507 us; speedup 1.0000x reference)
//
#include <hip/hip_runtime.h>
#include <math.h>

#define PN   298
#define PN2  88804   // 298*298
#define NB   4
#define NC   16
#define IMGS 64      // NB*NC

// ---------------- W table: Wc[u*298+n] = exp(-2*pi*i*u*n/298) ----------------
__global__ __launch_bounds__(256) void wtab_k(float2* __restrict__ Wc) {
  int t = blockIdx.x * 256 + threadIdx.x;
  if (t >= PN2) return;
  int u = t / PN, n = t % PN;
  int m = (u * n) % PN;
  float ang = (-2.0f * 3.14159265358979323846f / (float)PN) * (float)m;
  float s, c;
  sincosf(ang, &s, &c);
  Wc[t] = make_float2(c, s);
}

// ---------------- 1x1 reduce conv: x[4,64,256,256] -> cls[4,16,256,256] ------
__global__ __launch_bounds__(256) void reduce_k(const float* __restrict__ x,
                                                const float* __restrict__ w,
                                                const float* __restrict__ bias,
                                                float* __restrict__ cls) {
  __shared__ float ws_[1024];
  __shared__ float bs_[16];
  int t = threadIdx.x;
  for (int i = t; i < 1024; i += 256) ws_[i] = w[i];
  if (t < 16) bs_[t] = bias[t];
  __syncthreads();
  int b = blockIdx.y;
  int hw = blockIdx.x * 256 + t;
  const float* xb = x + ((size_t)b * 64) * 65536 + hw;
  float acc[16];
#pragma unroll
  for (int c = 0; c < 16; c++) acc[c] = bs_[c];
  for (int k = 0; k < 64; k++) {
    float xv = xb[(size_t)k * 65536];
#pragma unroll
    for (int c = 0; c < 16; c++) acc[c] = fmaf(ws_[c * 64 + k], xv, acc[c]);
  }
  float* ob = cls + ((size_t)b * 16) * 65536 + hw;
#pragma unroll
  for (int c = 0; c < 16; c++) ob[(size_t)c * 65536] = acc[c];
}

// ---------------- 3x3 VALID conv, 16->16 ch, optional leaky relu -------------
__global__ __launch_bounds__(256) void conv3_k(const float* __restrict__ in,
                                               const float* __restrict__ w,
                                               const float* __restrict__ bias,
                                               float* __restrict__ out,
                                               int HI, int WI, int relu) {
  __shared__ float ws_[2304];
  __shared__ float bs_[16];
  int t = threadIdx.x;
  for (int i = t; i < 2304; i += 256) ws_[i] = w[i];
  if (t < 16) bs_[t] = bias[t];
  __syncthreads();
  int HO = HI - 2, WO = WI - 2;
  int b = blockIdx.y;
  int idx = blockIdx.x * 256 + t;
  if (idx >= HO * WO) return;
  int y = idx / WO, xx = idx % WO;
  const float* ib = in + ((size_t)b * 16) * (size_t)(HI * WI);
  float acc[16];
#pragma unroll
  for (int c = 0; c < 16; c++) acc[c] = bs_[c];
  for (int ci = 0; ci < 16; ci++) {
    const float* p = ib + (size_t)ci * (HI * WI) + (size_t)y * WI + xx;
#pragma unroll
    for (int dy = 0; dy < 3; dy++) {
#pragma unroll
      for (int dx = 0; dx < 3; dx++) {
        float v = p[dy * WI + dx];
        int widx = ci * 9 + dy * 3 + dx;
#pragma unroll
        for (int co = 0; co < 16; co++)
          acc[co] = fmaf(ws_[co * 144 + widx], v, acc[co]);
      }
    }
  }
  float* ob = out + ((size_t)b * 16) * (size_t)(HO * WO) + (size_t)y * WO + xx;
#pragma unroll
  for (int co = 0; co < 16; co++) {
    float v = acc[co];
    if (relu) v = v > 0.f ? v : 0.1f * v;
    ob[(size_t)co * (HO * WO)] = v;
  }
}

// ---------------- adaptive avg pool 250x250 -> 3x3 ---------------------------
__global__ __launch_bounds__(256) void pool_k(const float* __restrict__ g,
                                              float* __restrict__ poolo) {
  int blk = blockIdx.x;            // b*144 + c*9 + ij
  int bc = blk / 9;
  int ij = blk % 9;
  int i = ij / 3, j = ij % 3;
  const int r0s[3] = {0, 83, 166}, r1s[3] = {84, 167, 250};
  int r0 = r0s[i], r1 = r1s[i], c0 = r0s[j], c1 = r1s[j];
  const float* p = g + (size_t)bc * 62500;
  int nc = c1 - c0;
  int tot = (r1 - r0) * nc;        // 7056
  float s = 0.f;
  for (int e = threadIdx.x; e < tot; e += 256) {
    int rr = e / nc, cc = e % nc;
    s += p[(r0 + rr) * 250 + c0 + cc];
  }
  for (int off = 32; off > 0; off >>= 1) s += __shfl_down(s, off, 64);
  __shared__ float red[4];
  int lane = threadIdx.x & 63, wid = threadIdx.x >> 6;
  if (lane == 0) red[wid] = s;
  __syncthreads();
  if (threadIdx.x == 0) poolo[blk] = (red[0] + red[1] + red[2] + red[3]) / (float)tot;
}

// ---------------- 1x1 conv on 3x3 + exp + mean-sub -> kernel_P ---------------
__global__ __launch_bounds__(256) void kp_k(const float* __restrict__ poolv,
                                            const float* __restrict__ w4,
                                            const float* __restrict__ b4,
                                            float* __restrict__ kp) {
  int b = blockIdx.x;
  int t = threadIdx.x;
  __shared__ float vals[144];
  __shared__ float w_[256];
  __shared__ float bb[16];
  if (t < 256) w_[t] = w4[t];
  if (t < 16) bb[t] = b4[t];
  __syncthreads();
  if (t < 144) {
    int c = t / 9, ij = t % 9;
    float a = bb[c];
    for (int k = 0; k < 16; k++)
      a = fmaf(w_[c * 16 + k], poolv[b * 144 + k * 9 + ij], a);
    vals[t] = expf(a);
  }
  __syncthreads();
  if (t < 144) {
    int c = t / 9;
    float m = 0.f;
#pragma unroll
    for (int q = 0; q < 9; q++) m += vals[c * 9 + q];
    kp[b * 144 + t] = vals[t] - m * (1.0f / 9.0f);
  }
}

// ---------------- edge pad cls (256) by 21 -> pad (298) ----------------------
__global__ __launch_bounds__(256) void pad_k(const float* __restrict__ cls,
                                             float* __restrict__ pad) {
  size_t idx = (size_t)blockIdx.x * 256 + threadIdx.x;
  if (idx >= (size_t)IMGS * PN2) return;
  int n = (int)(idx % PN);
  size_t rest = idx / PN;
  int m = (int)(rest % PN);
  size_t img = rest / PN;
  int sy = min(max(m - 21, 0), 255);
  int sx = min(max(n - 21, 0), 255);
  pad[idx] = cls[img * 65536 + (size_t)sy * 256 + sx];
}

// ---------------- Kf[b,u,v] = DFT of rolled 21x21 kernel ---------------------
__global__ __launch_bounds__(256) void kf_k(const float* __restrict__ ker,
                                            const float2* __restrict__ Wc,
                                            float2* __restrict__ Kf) {
  int b = blockIdx.y;
  __shared__ float ks[441];
  int t = threadIdx.x;
  for (int i = t; i < 441; i += 256) ks[i] = ker[b * 441 + i];
  __syncthreads();
  int uv = blockIdx.x * 256 + t;
  if (uv >= PN2) return;
  int u = uv / PN, v = uv % PN;
  int tu = (10 * u) % PN, tv = (10 * v) % PN;
  int t_i = (2 * PN - tu - tv) % PN;  // (-10u-10v) mod 298
  const float2* tw = Wc + PN;         // row 1: exp(-2 pi i t / 298)
  float ar = 0.f, ai = 0.f;
  for (int i = 0; i < 21; i++) {
    int tt = t_i;
#pragma unroll
    for (int j = 0; j < 21; j++) {
      float kv = ks[i * 21 + j];
      float2 wv = tw[tt];
      ar = fmaf(kv, wv.x, ar);
      ai = fmaf(kv, wv.y, ai);
      tt += v; if (tt >= PN) tt -= PN;
    }
    t_i += u; if (t_i >= PN) t_i -= PN;
  }
  Kf[(size_t)b * PN2 + uv] = make_float2(ar, ai);
}

// ---------------- G = conj(Kf)/(|Kf|^2+|Pf|^2) * F, in place on F -------------
__global__ __launch_bounds__(256) void gmul_k(float2* __restrict__ Fb,
                                              const float2* __restrict__ Kf,
                                              const float* __restrict__ kp,
                                              const float2* __restrict__ Wc) {
  int img = blockIdx.y;     // b*16 + c
  int b = img >> 4;
  __shared__ float kps[9];
  if (threadIdx.x < 9) kps[threadIdx.x] = kp[img * 9 + threadIdx.x];
  __syncthreads();
  int uv = blockIdx.x * 256 + threadIdx.x;
  if (uv >= PN2) return;
  int u = uv / PN, v = uv % PN;
  const float2* tw = Wc + PN;
  int um = (u == 0) ? 0 : (PN - u);
  int vm = (v == 0) ? 0 : (PN - v);
  int iu[3] = {um, 0, u}, jv[3] = {vm, 0, v};
  float pr = 0.f, pi = 0.f;
#pragma unroll
  for (int i = 0; i < 3; i++) {
#pragma unroll
    for (int j = 0; j < 3; j++) {
      int tt = iu[i] + jv[j];
      if (tt >= PN) tt -= PN;
      float kv = kps[i * 3 + j];
      float2 wv = tw[tt];
      pr = fmaf(kv, wv.x, pr);
      pi = fmaf(kv, wv.y, pi);
    }
  }
  float2 kf = Kf[(size_t)b * PN2 + uv];
  float denom = kf.x * kf.x + kf.y * kf.y + pr * pr + pi * pi;
  float inv = 1.0f / denom;
  float ir = kf.x * inv, ii = -kf.y * inv;
  size_t o = (size_t)img * PN2 + uv;
  float2 f = Fb[o];
  Fb[o] = make_float2(ir * f.x - ii * f.y, ir * f.y + ii * f.x);
}

// ---------------- tiled complex GEMM ------------------------------------------
// C[M,N] = scale * op(A)[M,K] * op(B)[K,N], batched over blockIdx.z.
// Strides aBS/bBS/cBS are in FLOAT units; lda/ldb/ldc in elements (row length).
template <bool AREAL, bool ACONJ, bool BCONJ, bool ROUT>
__global__ __launch_bounds__(256) void zgemm_k(
    const float* __restrict__ A, size_t aBS, int aRowOff, int lda,
    const float* __restrict__ B, size_t bBS, int ldb,
    float* __restrict__ Cc, size_t cBS, int ldc,
    int M, int N, int K, float scale) {
  __shared__ float2 As[16][66];
  __shared__ float2 Bs[16][66];
  int tx = threadIdx.x & 15, ty = threadIdx.x >> 4;
  int img = blockIdx.z;
  int row0 = blockIdx.y * 64, col0 = blockIdx.x * 64;
  const float* Ab = A + aBS * img;
  const float* Bb = B + bBS * img;
  float accx[4][4], accy[4][4];
#pragma unroll
  for (int i = 0; i < 4; i++)
#pragma unroll
    for (int j = 0; j < 4; j++) { accx[i][j] = 0.f; accy[i][j] = 0.f; }

  for (int k0 = 0; k0 < K; k0 += 16) {
    // stage A tile (64 rows x 16 k), transposed into As[k][row]
#pragma unroll
    for (int i = 0; i < 4; i++) {
      int e = threadIdx.x + i * 256;
      int r = e >> 4, k = e & 15;
      float2 v = make_float2(0.f, 0.f);
      int gk = k0 + k;
      if (row0 + r < M && gk < K) {
        int gr = row0 + r + aRowOff;
        if (AREAL) {
          v.x = Ab[(size_t)gr * lda + gk];
        } else {
          const float2* ap = (const float2*)Ab;
          v = ap[(size_t)gr * lda + gk];
          if (ACONJ) v.y = -v.y;
        }
      }
      As[k][r] = v;
    }
    // stage B tile (16 k x 64 cols)
#pragma unroll
    for (int i = 0; i < 4; i++) {
      int e = threadIdx.x + i * 256;
      int k = e >> 6, cc = e & 63;
      float2 v = make_float2(0.f, 0.f);
      int gk = k0 + k;
      if (gk < K && col0 + cc < N) {
        const float2* bp = (const float2*)Bb;
        v = bp[(size_t)gk * ldb + col0 + cc];
        if (BCONJ) v.y = -v.y;
      }
      Bs[k][cc] = v;
    }
    __syncthreads();
#pragma unroll
    for (int kk = 0; kk < 16; ++kk) {
      float2 a[4], bv[4];
#pragma unroll
      for (int i = 0; i < 4; i++) a[i] = As[kk][ty * 4 + i];
#pragma unroll
      for (int j = 0; j < 4; j++) bv[j] = Bs[kk][tx * 4 + j];
#pragma unroll
      for (int i = 0; i < 4; i++)
#pragma unroll
        for (int j = 0; j < 4; j++) {
          accx[i][j] = fmaf(a[i].x, bv[j].x, accx[i][j]);
          accx[i][j] = fmaf(-a[i].y, bv[j].y, accx[i][j]);
          if (!ROUT) {
            accy[i][j] = fmaf(a[i].x, bv[j].y, accy[i][j]);
            accy[i][j] = fmaf(a[i].y, bv[j].x, accy[i][j]);
          }
        }
    }
    __syncthreads();
  }
#pragma unroll
  for (int i = 0; i < 4; i++) {
#pragma unroll
    for (int j = 0; j < 4; j++) {
      int r = row0 + ty * 4 + i, cc = col0 + tx * 4 + j;
      if (r < M && cc < N) {
        if (ROUT) {
          Cc[cBS * img + (size_t)r * ldc + cc] = accx[i][j] * scale;
        } else {
          float2* cp = (float2*)(Cc + cBS * img);
          cp[(size_t)r * ldc + cc] = make_float2(accx[i][j] * scale, accy[i][j] * scale);
        }
      }
    }
  }
}

// ---------------- 1x1 expand conv with column crop ----------------------------
__global__ __launch_bounds__(256) void expand_k(const float* __restrict__ D,
                                                const float* __restrict__ w,
                                                const float* __restrict__ bias,
                                                float* __restrict__ out) {
  __shared__ float ws_[1024];
  __shared__ float bs_[64];
  int t = threadIdx.x;
  for (int i = t; i < 1024; i += 256) ws_[i] = w[i];
  if (t < 64) bs_[t] = bias[t];
  __syncthreads();
  int b = blockIdx.y;
  int hw = blockIdx.x * 256 + t;
  int h = hw >> 8, wcol = hw & 255;
  const float* Db = D + (size_t)b * 16 * 76288 + (size_t)h * PN + (wcol + 21);
  float d[16];
#pragma unroll
  for (int c = 0; c < 16; c++) d[c] = Db[(size_t)c * 76288];
  float* ob = out + ((size_t)b * 64) * 65536 + hw;
  for (int o = 0; o < 64; o++) {
    float a = bs_[o];
#pragma unroll
    for (int c = 0; c < 16; c++) a = fmaf(ws_[o * 16 + c], d[c], a);
    ob[(size_t)o * 65536] = a;
  }
}

extern "C" void kernel_launch(void* const* d_in, const int* in_sizes, int n_in,
                              void* d_out, int out_size, void* d_ws, size_t ws_size,
                              hipStream_t stream) {
  (void)in_sizes; (void)n_in; (void)out_size; (void)ws_size;
  const float* x        = (const float*)d_in[0];
  const float* kernel   = (const float*)d_in[1];
  const float* w_reduce = (const float*)d_in[2];
  const float* b_reduce = (const float*)d_in[3];
  const float* w_g1     = (const float*)d_in[4];
  const float* b_g1     = (const float*)d_in[5];
  const float* w_g2     = (const float*)d_in[6];
  const float* b_g2     = (const float*)d_in[7];
  const float* w_g3     = (const float*)d_in[8];
  const float* b_g3     = (const float*)d_in[9];
  const float* w_g4     = (const float*)d_in[10];
  const float* b_g4     = (const float*)d_in[11];
  const float* w_expand = (const float*)d_in[12];
  const float* b_expand = (const float*)d_in[13];
  float* out = (float*)d_out;

  // workspace layout (float offsets)
  float* ws_f = (float*)d_ws;
  float* cls   = ws_f;                       // 4,194,304
  float* g1    = ws_f + 4194304;             // 4,129,024
  float* g2    = ws_f + 8323328;             // 4,129,024
  float2* Fb   = (float2*)ws_f;              // aliases cls/g1/g2 (used after they're dead)
  float* T1f   = ws_f + 12452352;            // 11,366,912 floats (complex T1/T2)
  float* padb  = ws_f + 23819264;            // 5,683,456 (later reused for D real)
  float* Wcf   = ws_f + 29502720;            // 177,608 floats (complex W)
  float2* Wc2  = (float2*)Wcf;
  float2* Kf2  = (float2*)(ws_f + 29680328); // 710,432 floats
  float* poolb = ws_f + 30390760;            // 576
  float* kpb   = ws_f + 30391336;            // 576

  // 1. DFT matrix
  wtab_k<<<dim3((PN2 + 255) / 256), 256, 0, stream>>>(Wc2);
  // 2. reduce conv
  reduce_k<<<dim3(256, NB), 256, 0, stream>>>(x, w_reduce, b_reduce, cls);
  // 3-5. g-chain
  conv3_k<<<dim3((254 * 254 + 255) / 256, NB), 256, 0, stream>>>(cls, w_g1, b_g1, g1, 256, 256, 1);
  conv3_k<<<dim3((252 * 252 + 255) / 256, NB), 256, 0, stream>>>(g1, w_g2, b_g2, g2, 254, 254, 1);
  conv3_k<<<dim3((250 * 250 + 255) / 256, NB), 256, 0, stream>>>(g2, w_g3, b_g3, g1, 252, 252, 0);
  // 6. adaptive pool 3x3
  pool_k<<<dim3(NB * NC * 9), 256, 0, stream>>>(g1, poolb);
  // 7. kernel_P
  kp_k<<<dim3(NB), 256, 0, stream>>>(poolb, w_g4, b_g4, kpb);
  // 8. edge pad
  pad_k<<<dim3((IMGS * PN2 + 255) / 256), 256, 0, stream>>>(cls, padb);
  // 9. Kf
  kf_k<<<dim3((PN2 + 255) / 256, NB), 256, 0, stream>>>(kernel, Wc2, Kf2);
  // 10. forward pass 1: T1 = pad @ W   (A real)
  zgemm_k<true, false, false, false><<<dim3(5, 5, IMGS), 256, 0, stream>>>(
      padb, (size_t)PN2, 0, PN, Wcf, 0, PN, T1f, (size_t)2 * PN2, PN, PN, PN, PN, 1.0f);
  // 11. forward pass 2: F = W @ T1  -> Fb (aliased base region, now free)
  zgemm_k<false, false, false, false><<<dim3(5, 5, IMGS), 256, 0, stream>>>(
      Wcf, 0, 0, PN, T1f, (size_t)2 * PN2, PN, (float*)Fb, (size_t)2 * PN2, PN, PN, PN, PN, 1.0f);
  // 12. Wiener multiply in place
  gmul_k<<<dim3((PN2 + 255) / 256, IMGS), 256, 0, stream>>>(Fb, Kf2, kpb, Wc2);
  // 13. inverse pass 1: T2 = G @ conj(W) -> T1 buffer
  zgemm_k<false, false, true, false><<<dim3(5, 5, IMGS), 256, 0, stream>>>(
      (float*)Fb, (size_t)2 * PN2, 0, PN, Wcf, 0, PN, T1f, (size_t)2 * PN2, PN, PN, PN, PN, 1.0f);
  // 14. inverse pass 2 (real part, cropped rows 21..276): D = Re(conj(W)[21:277,:] @ T2)/N^2
  zgemm_k<false, true, false, true><<<dim3(5, 4, IMGS), 256, 0, stream>>>(
      Wcf, 0, 21, PN, T1f, (size_t)2 * PN2, PN, padb, (size_t)256 * PN, PN,
      256, PN, PN, 1.0f / (float)PN2);
  // 15. expand conv (+ column crop)
  expand_k<<<dim3(256, NB), 256, 0, stream>>>(padb, w_expand, b_expand, out);
}

// Round 2
// 572.607 us; speedup vs baseline: 1.8765x; 1.8765x over previous
//
#include <hip/hip_runtime.h>
#include <math.h>

#define PN    298
#define LDW   304          // Wc row stride (float2) / padb row stride (floats)
#define WROWS 320
#define LDH   160          // half-plane complex row stride (float2)
#define GSLAB (320*160)    // float2 per image for T1 / G
#define ESLAB (256*160)    // float2 per image for E
#define LDD   256
#define DSLAB (256*256)
#define NB    4
#define IMGS  64

// ---------------- W table: Wc[u][n] = exp(-2*pi*i*u*n/298), zero-padded ------
__global__ __launch_bounds__(256) void wtab_k(float2* __restrict__ Wc) {
  int t = blockIdx.x * 256 + threadIdx.x;
  if (t >= WROWS * LDW) return;
  int u = t / LDW, n = t % LDW;
  float2 v = make_float2(0.f, 0.f);
  if (u < PN && n < PN) {
    int m = (u * n) % PN;
    float ang = (-2.0f * 3.14159265358979323846f / (float)PN) * (float)m;
    float s, c;
    sincosf(ang, &s, &c);
    v = make_float2(c, s);
  }
  Wc[t] = v;
}

// ---------------- 1x1 reduce conv: x[4,64,256,256] -> cls[4,16,256,256] ------
__global__ __launch_bounds__(256) void reduce_k(const float* __restrict__ x,
                                                const float* __restrict__ w,
                                                const float* __restrict__ bias,
                                                float* __restrict__ cls) {
  __shared__ float ws_[1024];
  __shared__ float bs_[16];
  int t = threadIdx.x;
  for (int i = t; i < 1024; i += 256) ws_[i] = w[i];
  if (t < 16) bs_[t] = bias[t];
  __syncthreads();
  int b = blockIdx.y;
  int hw = blockIdx.x * 256 + t;
  const float* xb = x + ((size_t)b * 64) * 65536 + hw;
  float acc[16];
#pragma unroll
  for (int c = 0; c < 16; c++) acc[c] = bs_[c];
  for (int k = 0; k < 64; k++) {
    float xv = xb[(size_t)k * 65536];
#pragma unroll
    for (int c = 0; c < 16; c++) acc[c] = fmaf(ws_[c * 64 + k], xv, acc[c]);
  }
  float* ob = cls + ((size_t)b * 16) * 65536 + hw;
#pragma unroll
  for (int c = 0; c < 16; c++) ob[(size_t)c * 65536] = acc[c];
}

// ---------------- 3x3 VALID conv, 16->16 ch, optional leaky relu -------------
__global__ __launch_bounds__(256) void conv3_k(const float* __restrict__ in,
                                               const float* __restrict__ w,
                                               const float* __restrict__ bias,
                                               float* __restrict__ out,
                                               int HI, int WI, int relu) {
  __shared__ float ws_[2304];
  __shared__ float bs_[16];
  int t = threadIdx.x;
  for (int i = t; i < 2304; i += 256) ws_[i] = w[i];
  if (t < 16) bs_[t] = bias[t];
  __syncthreads();
  int HO = HI - 2, WO = WI - 2;
  int b = blockIdx.y;
  int idx = blockIdx.x * 256 + t;
  if (idx >= HO * WO) return;
  int y = idx / WO, xx = idx % WO;
  const float* ib = in + ((size_t)b * 16) * (size_t)(HI * WI);
  float acc[16];
#pragma unroll
  for (int c = 0; c < 16; c++) acc[c] = bs_[c];
  for (int ci = 0; ci < 16; ci++) {
    const float* p = ib + (size_t)ci * (HI * WI) + (size_t)y * WI + xx;
#pragma unroll
    for (int dy = 0; dy < 3; dy++) {
#pragma unroll
      for (int dx = 0; dx < 3; dx++) {
        float v = p[dy * WI + dx];
        int widx = ci * 9 + dy * 3 + dx;
#pragma unroll
        for (int co = 0; co < 16; co++)
          acc[co] = fmaf(ws_[co * 144 + widx], v, acc[co]);
      }
    }
  }
  float* ob = out + ((size_t)b * 16) * (size_t)(HO * WO) + (size_t)y * WO + xx;
#pragma unroll
  for (int co = 0; co < 16; co++) {
    float v = acc[co];
    if (relu) v = v > 0.f ? v : 0.1f * v;
    ob[(size_t)co * (HO * WO)] = v;
  }
}

// ---------------- adaptive avg pool 250x250 -> 3x3 ---------------------------
__global__ __launch_bounds__(256) void pool_k(const float* __restrict__ g,
                                              float* __restrict__ poolo) {
  int blk = blockIdx.x;
  int bc = blk / 9;
  int ij = blk % 9;
  int i = ij / 3, j = ij % 3;
  const int r0s[3] = {0, 83, 166}, r1s[3] = {84, 167, 250};
  int r0 = r0s[i], r1 = r1s[i], c0 = r0s[j], c1 = r1s[j];
  const float* p = g + (size_t)bc * 62500;
  int nc = c1 - c0;
  int tot = (r1 - r0) * nc;
  float s = 0.f;
  for (int e = threadIdx.x; e < tot; e += 256) {
    int rr = e / nc, cc = e % nc;
    s += p[(r0 + rr) * 250 + c0 + cc];
  }
  for (int off = 32; off > 0; off >>= 1) s += __shfl_down(s, off, 64);
  __shared__ float red[4];
  int lane = threadIdx.x & 63, wid = threadIdx.x >> 6;
  if (lane == 0) red[wid] = s;
  __syncthreads();
  if (threadIdx.x == 0) poolo[blk] = (red[0] + red[1] + red[2] + red[3]) / (float)tot;
}

// ---------------- 1x1 conv on 3x3 + exp + mean-sub -> kernel_P ---------------
__global__ __launch_bounds__(256) void kp_k(const float* __restrict__ poolv,
                                            const float* __restrict__ w4,
                                            const float* __restrict__ b4,
                                            float* __restrict__ kp) {
  int b = blockIdx.x;
  int t = threadIdx.x;
  __shared__ float vals[144];
  __shared__ float w_[256];
  __shared__ float bb[16];
  if (t < 256) w_[t] = w4[t];
  if (t < 16) bb[t] = b4[t];
  __syncthreads();
  if (t < 144) {
    int c = t / 9, ij = t % 9;
    float a = bb[c];
    for (int k = 0; k < 16; k++)
      a = fmaf(w_[c * 16 + k], poolv[b * 144 + k * 9 + ij], a);
    vals[t] = expf(a);
  }
  __syncthreads();
  if (t < 144) {
    int c = t / 9;
    float m = 0.f;
#pragma unroll
    for (int q = 0; q < 9; q++) m += vals[c * 9 + q];
    kp[b * 144 + t] = vals[t] - m * (1.0f / 9.0f);
  }
}

// ---------------- edge pad cls (256) -> pad [320 x 304] ----------------------
__global__ __launch_bounds__(256) void pad_k(const float* __restrict__ cls,
                                             float* __restrict__ pad) {
  size_t idx = (size_t)blockIdx.x * 256 + threadIdx.x;
  if (idx >= (size_t)IMGS * WROWS * LDW) return;
  int n = (int)(idx % LDW);
  size_t rest = idx / LDW;
  int m = (int)(rest % WROWS);
  size_t img = rest / WROWS;
  int sy = min(max(m - 21, 0), 255);
  int sx = min(max(n - 21, 0), 255);
  pad[idx] = cls[img * 65536 + (size_t)sy * 256 + sx];
}

// ---------------- Kf[b,u,v] (half-plane v<150) = DFT of rolled 21x21 kernel --
__global__ __launch_bounds__(256) void kf_k(const float* __restrict__ ker,
                                            const float2* __restrict__ Wc,
                                            float2* __restrict__ Kf) {
  int b = blockIdx.y;
  __shared__ float ks[441];
  int t = threadIdx.x;
  for (int i = t; i < 441; i += 256) ks[i] = ker[b * 441 + i];
  __syncthreads();
  int uv = blockIdx.x * 256 + t;
  if (uv >= PN * 150) return;
  int u = uv / 150, v = uv % 150;
  int tu = (10 * u) % PN, tv = (10 * v) % PN;
  int t_i = (2 * PN - tu - tv) % PN;
  const float2* tw = Wc + LDW;
  float ar = 0.f, ai = 0.f;
  for (int i = 0; i < 21; i++) {
    int tt = t_i;
#pragma unroll
    for (int j = 0; j < 21; j++) {
      float kv = ks[i * 21 + j];
      float2 wv = tw[tt];
      ar = fmaf(kv, wv.x, ar);
      ai = fmaf(kv, wv.y, ai);
      tt += v; if (tt >= PN) tt -= PN;
    }
    t_i += u; if (t_i >= PN) t_i -= PN;
  }
  Kf[(size_t)b * (PN * 150) + uv] = make_float2(ar, ai);
}

// ---------------- Wiener multiply in place on half-plane G -------------------
__global__ __launch_bounds__(256) void gmul_k(float2* __restrict__ Gb,
                                              const float2* __restrict__ Kf,
                                              const float* __restrict__ kp,
                                              const float2* __restrict__ Wc) {
  int img = blockIdx.y;
  int b = img >> 4;
  __shared__ float kps[9];
  if (threadIdx.x < 9) kps[threadIdx.x] = kp[img * 9 + threadIdx.x];
  __syncthreads();
  int idx = blockIdx.x * 256 + threadIdx.x;
  if (idx >= PN * 150) return;
  int u = idx / 150, v = idx % 150;
  const float2* tw = Wc + LDW;
  int um = (u == 0) ? 0 : (PN - u);
  int vm = (v == 0) ? 0 : (PN - v);
  int iu[3] = {um, 0, u}, jv[3] = {vm, 0, v};
  float pr = 0.f, pi = 0.f;
#pragma unroll
  for (int i = 0; i < 3; i++) {
#pragma unroll
    for (int j = 0; j < 3; j++) {
      int tt = iu[i] + jv[j];
      if (tt >= PN) tt -= PN;
      float kv = kps[i * 3 + j];
      float2 wv = tw[tt];
      pr = fmaf(kv, wv.x, pr);
      pi = fmaf(kv, wv.y, pi);
    }
  }
  float2 kf = Kf[(size_t)b * (PN * 150) + idx];
  float denom = kf.x * kf.x + kf.y * kf.y + pr * pr + pi * pi;
  float inv = 1.0f / denom;
  float ir = kf.x * inv, ii = -kf.y * inv;
  size_t o = (size_t)img * GSLAB + (size_t)u * LDH + v;
  float2 f = Gb[o];
  Gb[o] = make_float2(ir * f.x - ii * f.y, ir * f.y + ii * f.x);
}

// ---------------- P1: T1[m,v] = sum_n pad[m,n] * W[n,v]  (A real) ------------
__global__ __launch_bounds__(256) void gemm_p1(const float* __restrict__ A,
                                               const float2* __restrict__ W,
                                               float2* __restrict__ C) {
  __shared__ float  As[16][68];
  __shared__ float2 Bs[16][34];
  int tid = threadIdx.x;
  int img = blockIdx.z;
  int row0 = blockIdx.y * 64, col0 = blockIdx.x * 32;
  const float* Ab = A + (size_t)img * (WROWS * LDW);
  int tx = tid & 15, ty = tid >> 4;
  float ar[4][2], ai[4][2];
#pragma unroll
  for (int i = 0; i < 4; i++)
#pragma unroll
    for (int j = 0; j < 2; j++) { ar[i][j] = 0.f; ai[i][j] = 0.f; }

  for (int k0 = 0; k0 < 304; k0 += 16) {
    {
      int r = tid >> 2, kq = (tid & 3) << 2;
      float4 a4 = *(const float4*)(Ab + (size_t)(row0 + r) * LDW + k0 + kq);
      As[kq + 0][r] = a4.x; As[kq + 1][r] = a4.y;
      As[kq + 2][r] = a4.z; As[kq + 3][r] = a4.w;
    }
    {
      int k = tid >> 4, c2 = (tid & 15) << 1;
      float4 b4 = *(const float4*)(W + (size_t)(k0 + k) * LDW + col0 + c2);
      Bs[k][c2]     = make_float2(b4.x, b4.y);
      Bs[k][c2 + 1] = make_float2(b4.z, b4.w);
    }
    __syncthreads();
#pragma unroll
    for (int kk = 0; kk < 16; ++kk) {
      float4 a4 = *(const float4*)&As[kk][ty * 4];
      float4 b4 = *(const float4*)&Bs[kk][tx * 2];
      float a[4] = {a4.x, a4.y, a4.z, a4.w};
      float bxr[2] = {b4.x, b4.z}, bxi[2] = {b4.y, b4.w};
#pragma unroll
      for (int i = 0; i < 4; i++)
#pragma unroll
        for (int j = 0; j < 2; j++) {
          ar[i][j] = fmaf(a[i], bxr[j], ar[i][j]);
          ai[i][j] = fmaf(a[i], bxi[j], ai[i][j]);
        }
    }
    __syncthreads();
  }
  float2* Cb = C + (size_t)img * GSLAB;
#pragma unroll
  for (int i = 0; i < 4; i++) {
    int r = row0 + ty * 4 + i, c = col0 + tx * 2;
    bool v0 = c < 150, v1 = c + 1 < 150;
    float4 st;
    st.x = v0 ? ar[i][0] : 0.f; st.y = v0 ? ai[i][0] : 0.f;
    st.z = v1 ? ar[i][1] : 0.f; st.w = v1 ? ai[i][1] : 0.f;
    *(float4*)(Cb + (size_t)r * LDH + c) = st;
  }
}

// ---------------- P2/P3: C[r,v] = sum_k (conj?)W[r+off,k] * B[k,v] -----------
template <bool ACONJ>
__global__ __launch_bounds__(256) void zgemm_w(const float2* __restrict__ W,
                                               int aRowOff,
                                               const float2* __restrict__ B,
                                               float2* __restrict__ C,
                                               size_t bSlab, size_t cSlab) {
  __shared__ float2 As[16][66];
  __shared__ float2 Bs[16][34];
  int tid = threadIdx.x;
  int img = blockIdx.z;
  int row0 = blockIdx.y * 64, col0 = blockIdx.x * 32;
  const float2* Bb = B + (size_t)img * bSlab;
  int tx = tid & 15, ty = tid >> 4;
  float ar[4][2], ai[4][2];
#pragma unroll
  for (int i = 0; i < 4; i++)
#pragma unroll
    for (int j = 0; j < 2; j++) { ar[i][j] = 0.f; ai[i][j] = 0.f; }

  for (int k0 = 0; k0 < 304; k0 += 16) {
#pragma unroll
    for (int s = 0; s < 2; s++) {
      int e = tid + s * 256;
      int r = e >> 3, kp = (e & 7) << 1;
      float4 a4 = *(const float4*)(W + (size_t)(row0 + r + aRowOff) * LDW + k0 + kp);
      float i1 = ACONJ ? -a4.y : a4.y;
      float i2 = ACONJ ? -a4.w : a4.w;
      As[kp][r]     = make_float2(a4.x, i1);
      As[kp + 1][r] = make_float2(a4.z, i2);
    }
    {
      int k = tid >> 4, c2 = (tid & 15) << 1;
      float4 b4 = *(const float4*)(Bb + (size_t)(k0 + k) * LDH + col0 + c2);
      Bs[k][c2]     = make_float2(b4.x, b4.y);
      Bs[k][c2 + 1] = make_float2(b4.z, b4.w);
    }
    __syncthreads();
#pragma unroll
    for (int kk = 0; kk < 16; ++kk) {
      float4 a01 = *(const float4*)&As[kk][ty * 4];
      float4 a23 = *(const float4*)&As[kk][ty * 4 + 2];
      float4 b4  = *(const float4*)&Bs[kk][tx * 2];
      float axr[4] = {a01.x, a01.z, a23.x, a23.z};
      float axi[4] = {a01.y, a01.w, a23.y, a23.w};
      float bxr[2] = {b4.x, b4.z}, bxi[2] = {b4.y, b4.w};
#pragma unroll
      for (int i = 0; i < 4; i++)
#pragma unroll
        for (int j = 0; j < 2; j++) {
          ar[i][j] = fmaf(axr[i], bxr[j], ar[i][j]);
          ar[i][j] = fmaf(-axi[i], bxi[j], ar[i][j]);
          ai[i][j] = fmaf(axr[i], bxi[j], ai[i][j]);
          ai[i][j] = fmaf(axi[i], bxr[j], ai[i][j]);
        }
    }
    __syncthreads();
  }
  float2* Cb = C + (size_t)img * cSlab;
#pragma unroll
  for (int i = 0; i < 4; i++) {
    int r = row0 + ty * 4 + i, c = col0 + tx * 2;
    bool v0 = c < 150, v1 = c + 1 < 150;
    float4 st;
    st.x = v0 ? ar[i][0] : 0.f; st.y = v0 ? ai[i][0] : 0.f;
    st.z = v1 ? ar[i][1] : 0.f; st.w = v1 ? ai[i][1] : 0.f;
    *(float4*)(Cb + (size_t)r * LDH + c) = st;
  }
}

// ---------------- P4: D[m,n] = (1/N^2) sum_k E'[m,k] * B'[k,n+21] ------------
__global__ __launch_bounds__(256) void gemm_p4(const float* __restrict__ Ef,
                                               const float2* __restrict__ W,
                                               float* __restrict__ D) {
  __shared__ float As[16][68];
  __shared__ float Bs[16][68];
  int tid = threadIdx.x;
  int img = blockIdx.z;
  int row0 = blockIdx.y * 64, col0 = blockIdx.x * 64;
  const float* Ab = Ef + (size_t)img * (size_t)(ESLAB * 2);
  int tx = tid & 15, ty = tid >> 4;
  float acc[4][4];
#pragma unroll
  for (int i = 0; i < 4; i++)
#pragma unroll
    for (int j = 0; j < 4; j++) acc[i][j] = 0.f;

  for (int k0 = 0; k0 < 304; k0 += 16) {
    {
      int r = tid >> 2, kq = (tid & 3) << 2;
      float4 a4 = *(const float4*)(Ab + (size_t)(row0 + r) * 320 + k0 + kq);
      As[kq][r] = a4.x; As[kq + 1][r] = a4.y;
      As[kq + 2][r] = a4.z; As[kq + 3][r] = a4.w;
    }
#pragma unroll
    for (int s = 0; s < 2; s++) {
      int e = tid + s * 256;
      int vv = e >> 6, cc = e & 63;
      int v = (k0 >> 1) + vv;
      float2 w = W[(size_t)v * LDW + col0 + cc + 21];
      float fac = (v >= 1 && v < 149) ? 2.f : (v < 150 ? 1.f : 0.f);
      Bs[2 * vv][cc]     = fac * w.x;
      Bs[2 * vv + 1][cc] = fac * w.y;
    }
    __syncthreads();
#pragma unroll
    for (int kk = 0; kk < 16; ++kk) {
      float4 a4 = *(const float4*)&As[kk][ty * 4];
      float4 b4 = *(const float4*)&Bs[kk][tx * 4];
      float a[4] = {a4.x, a4.y, a4.z, a4.w};
      float b[4] = {b4.x, b4.y, b4.z, b4.w};
#pragma unroll
      for (int i = 0; i < 4; i++)
#pragma unroll
        for (int j = 0; j < 4; j++) acc[i][j] = fmaf(a[i], b[j], acc[i][j]);
    }
    __syncthreads();
  }
  float* Db = D + (size_t)img * DSLAB;
  const float sc = 1.0f / (float)(PN * PN);
#pragma unroll
  for (int i = 0; i < 4; i++) {
    float4 st = make_float4(acc[i][0] * sc, acc[i][1] * sc, acc[i][2] * sc, acc[i][3] * sc);
    *(float4*)(Db + (size_t)(row0 + ty * 4 + i) * LDD + col0 + tx * 4) = st;
  }
}

// ---------------- 1x1 expand conv ---------------------------------------------
__global__ __launch_bounds__(256) void expand_k(const float* __restrict__ D,
                                                const float* __restrict__ w,
                                                const float* __restrict__ bias,
                                                float* __restrict__ out) {
  __shared__ float ws_[1024];
  __shared__ float bs_[64];
  int t = threadIdx.x;
  for (int i = t; i < 1024; i += 256) ws_[i] = w[i];
  if (t < 64) bs_[t] = bias[t];
  __syncthreads();
  int b = blockIdx.y;
  int hw = blockIdx.x * 256 + t;
  const float* Db = D + (size_t)b * 16 * DSLAB + hw;
  float d[16];
#pragma unroll
  for (int c = 0; c < 16; c++) d[c] = Db[(size_t)c * DSLAB];
  float* ob = out + ((size_t)b * 64) * 65536 + hw;
  for (int o = 0; o < 64; o++) {
    float a = bs_[o];
#pragma unroll
    for (int c = 0; c < 16; c++) a = fmaf(ws_[o * 16 + c], d[c], a);
    ob[(size_t)o * 65536] = a;
  }
}

extern "C" void kernel_launch(void* const* d_in, const int* in_sizes, int n_in,
                              void* d_out, int out_size, void* d_ws, size_t ws_size,
                              hipStream_t stream) {
  (void)in_sizes; (void)n_in; (void)out_size; (void)ws_size;
  const float* x        = (const float*)d_in[0];
  const float* kernel   = (const float*)d_in[1];
  const float* w_reduce = (const float*)d_in[2];
  const float* b_reduce = (const float*)d_in[3];
  const float* w_g1     = (const float*)d_in[4];
  const float* b_g1     = (const float*)d_in[5];
  const float* w_g2     = (const float*)d_in[6];
  const float* b_g2     = (const float*)d_in[7];
  const float* w_g3     = (const float*)d_in[8];
  const float* b_g3     = (const float*)d_in[9];
  const float* w_g4     = (const float*)d_in[10];
  const float* b_g4     = (const float*)d_in[11];
  const float* w_expand = (const float*)d_in[12];
  const float* b_expand = (const float*)d_in[13];
  float* out = (float*)d_out;

  // workspace layout (float offsets):
  //  [0 .. 12,452,352): cls + g1 + g2, later reused for G (6.55M floats)
  //  [12,452,352 .. 18,678,272): padb (6.23M), later reused for D (4.19M)
  //  [18,678,272 .. 18,872,832): Wc
  //  [18,872,832 .. 25,426,432): T1 (6.55M), later reused for E (5.24M)
  //  [25,426,432 .. ): Kf, pool, kp   (total ~103 MB)
  float* ws_f = (float*)d_ws;
  float*  cls   = ws_f;
  float*  g1    = ws_f + 4194304;
  float*  g2    = ws_f + 8323328;
  float2* Gb    = (float2*)ws_f;
  float*  padb  = ws_f + 12452352;
  float*  Db    = ws_f + 12452352;
  float2* Wc2   = (float2*)(ws_f + 18678272);
  float2* T1    = (float2*)(ws_f + 18872832);
  float2* Eb    = (float2*)(ws_f + 18872832);
  float2* Kf2   = (float2*)(ws_f + 25426432);
  float*  poolb = ws_f + 26141632;
  float*  kpb   = ws_f + 26142208;

  wtab_k<<<dim3((WROWS * LDW) / 256), 256, 0, stream>>>(Wc2);
  reduce_k<<<dim3(256, NB), 256, 0, stream>>>(x, w_reduce, b_reduce, cls);
  conv3_k<<<dim3((254 * 254 + 255) / 256, NB), 256, 0, stream>>>(cls, w_g1, b_g1, g1, 256, 256, 1);
  conv3_k<<<dim3((252 * 252 + 255) / 256, NB), 256, 0, stream>>>(g1, w_g2, b_g2, g2, 254, 254, 1);
  conv3_k<<<dim3((250 * 250 + 255) / 256, NB), 256, 0, stream>>>(g2, w_g3, b_g3, g1, 252, 252, 0);
  pool_k<<<dim3(NB * 16 * 9), 256, 0, stream>>>(g1, poolb);
  kp_k<<<dim3(NB), 256, 0, stream>>>(poolb, w_g4, b_g4, kpb);
  pad_k<<<dim3((IMGS * WROWS * LDW) / 256), 256, 0, stream>>>(cls, padb);
  kf_k<<<dim3((PN * 150 + 255) / 256, NB), 256, 0, stream>>>(kernel, Wc2, Kf2);
  gemm_p1<<<dim3(5, 5, IMGS), 256, 0, stream>>>(padb, Wc2, T1);
  zgemm_w<false><<<dim3(5, 5, IMGS), 256, 0, stream>>>(Wc2, 0, T1, Gb, GSLAB, GSLAB);
  gmul_k<<<dim3((PN * 150 + 255) / 256, IMGS), 256, 0, stream>>>(Gb, Kf2, kpb, Wc2);
  zgemm_w<true><<<dim3(5, 4, IMGS), 256, 0, stream>>>(Wc2, 21, Gb, Eb, GSLAB, ESLAB);
  gemm_p4<<<dim3(4, 4, IMGS), 256, 0, stream>>>((const float*)Eb, Wc2, Db);
  expand_k<<<dim3(256, NB), 256, 0, stream>>>(Db, w_expand, b_expand, out);
}

// Round 4
// 544.930 us; speedup vs baseline: 1.9718x; 1.0508x over previous
//
#include <hip/hip_runtime.h>
#include <math.h>

typedef unsigned short u16;
typedef unsigned int   u32;
typedef __attribute__((ext_vector_type(8))) short bf16x8;
typedef __attribute__((ext_vector_type(4))) float f32x4;

#define NB    4
#define IMGS  64
#define DSLAB (256*256)

// ---------- bf16 split helpers ----------
__device__ __forceinline__ u16 f2bf(float x) {
  u32 u = __float_as_uint(x);
  u += 0x7fffu + ((u >> 16) & 1u);
  return (u16)(u >> 16);
}
__device__ __forceinline__ float bf2f(u16 h) { return __uint_as_float(((u32)h) << 16); }
__device__ __forceinline__ void split3(float x, u16& h, u16& m, u16& l) {
  h = f2bf(x); float r = x - bf2f(h);
  m = f2bf(r); float r2 = r - bf2f(m);
  l = f2bf(r2);
}

// ---------- tiny twiddle table tw[t] = exp(-2*pi*i*t/298) ----------
__global__ __launch_bounds__(256) void twtab_k(float2* __restrict__ tw) {
  int t = blockIdx.x * 256 + threadIdx.x;
  if (t >= 298) return;
  float ang = (-2.0f * 3.14159265358979323846f / 298.0f) * (float)t;
  float s, c; sincosf(ang, &s, &c);
  tw[t] = make_float2(c, s);
}

// ---------- W split planes: Wr/Wi [3][320][320] u16, Wri [3][320][320] u32 ----
__global__ __launch_bounds__(256) void wsplit_k(u16* __restrict__ Wr, u16* __restrict__ Wi,
                                                u32* __restrict__ Wri) {
  int idx = blockIdx.x * 256 + threadIdx.x;
  if (idx >= 102400) return;
  int u = idx / 320, n = idx % 320;
  float cr = 0.f, ci = 0.f;
  if (u < 298 && n < 298) {
    int m = (u * n) % 298;
    float ang = (-2.0f * 3.14159265358979323846f / 298.0f) * (float)m;
    float s, c; sincosf(ang, &s, &c);
    cr = c; ci = s;
  }
  u16 hr[3], hi[3];
  split3(cr, hr[0], hr[1], hr[2]);
  split3(ci, hi[0], hi[1], hi[2]);
#pragma unroll
  for (int p = 0; p < 3; p++) {
    Wr[p * 102400 + idx] = hr[p];
    Wi[p * 102400 + idx] = hi[p];
    Wri[p * 102400 + idx] = (u32)hr[p] | ((u32)hi[p] << 16);
  }
}

// ---------- B4t planes [3][256 n][320 k'] : fac(v)*W[v][n+21].p at k'=2v+p ----
// v in [0,160) only: 2v stays inside the 320-wide row (v>=150 rows are zero).
__global__ __launch_bounds__(256) void b4t_k(u16* __restrict__ b4) {
  int idx = blockIdx.x * 256 + threadIdx.x;
  if (idx >= 40960) return;
  int v = idx / 256, n = idx % 256;
  float re = 0.f, im = 0.f;
  if (v < 150) {
    int m = (v * (n + 21)) % 298;
    float ang = (-2.0f * 3.14159265358979323846f / 298.0f) * (float)m;
    float s, c; sincosf(ang, &s, &c);
    float fac = (v >= 1 && v < 149) ? 2.f : 1.f;
    re = fac * c; im = fac * s;
  }
  u16 hr[3], hi[3];
  split3(re, hr[0], hr[1], hr[2]);
  split3(im, hi[0], hi[1], hi[2]);
  size_t o = (size_t)n * 320 + 2 * v;
#pragma unroll
  for (int p = 0; p < 3; p++) {
    b4[p * 81920 + o] = hr[p];
    b4[p * 81920 + o + 1] = hi[p];
  }
}

// ---------- 1x1 reduce conv ----------
__global__ __launch_bounds__(256) void reduce_k(const float* __restrict__ x,
                                                const float* __restrict__ w,
                                                const float* __restrict__ bias,
                                                float* __restrict__ cls) {
  __shared__ float ws_[1024];
  __shared__ float bs_[16];
  int t = threadIdx.x;
  for (int i = t; i < 1024; i += 256) ws_[i] = w[i];
  if (t < 16) bs_[t] = bias[t];
  __syncthreads();
  int b = blockIdx.y;
  int hw = blockIdx.x * 256 + t;
  const float* xb = x + ((size_t)b * 64) * 65536 + hw;
  float acc[16];
#pragma unroll
  for (int c = 0; c < 16; c++) acc[c] = bs_[c];
  for (int k = 0; k < 64; k++) {
    float xv = xb[(size_t)k * 65536];
#pragma unroll
    for (int c = 0; c < 16; c++) acc[c] = fmaf(ws_[c * 64 + k], xv, acc[c]);
  }
  float* ob = cls + ((size_t)b * 16) * 65536 + hw;
#pragma unroll
  for (int c = 0; c < 16; c++) ob[(size_t)c * 65536] = acc[c];
}

// ---------- 3x3 VALID conv ----------
__global__ __launch_bounds__(256) void conv3_k(const float* __restrict__ in,
                                               const float* __restrict__ w,
                                               const float* __restrict__ bias,
                                               float* __restrict__ out,
                                               int HI, int WI, int relu) {
  __shared__ float ws_[2304];
  __shared__ float bs_[16];
  int t = threadIdx.x;
  for (int i = t; i < 2304; i += 256) ws_[i] = w[i];
  if (t < 16) bs_[t] = bias[t];
  __syncthreads();
  int HO = HI - 2, WO = WI - 2;
  int b = blockIdx.y;
  int idx = blockIdx.x * 256 + t;
  if (idx >= HO * WO) return;
  int y = idx / WO, xx = idx % WO;
  const float* ib = in + ((size_t)b * 16) * (size_t)(HI * WI);
  float acc[16];
#pragma unroll
  for (int c = 0; c < 16; c++) acc[c] = bs_[c];
  for (int ci = 0; ci < 16; ci++) {
    const float* p = ib + (size_t)ci * (HI * WI) + (size_t)y * WI + xx;
#pragma unroll
    for (int dy = 0; dy < 3; dy++) {
#pragma unroll
      for (int dx = 0; dx < 3; dx++) {
        float v = p[dy * WI + dx];
        int widx = ci * 9 + dy * 3 + dx;
#pragma unroll
        for (int co = 0; co < 16; co++)
          acc[co] = fmaf(ws_[co * 144 + widx], v, acc[co]);
      }
    }
  }
  float* ob = out + ((size_t)b * 16) * (size_t)(HO * WO) + (size_t)y * WO + xx;
#pragma unroll
  for (int co = 0; co < 16; co++) {
    float v = acc[co];
    if (relu) v = v > 0.f ? v : 0.1f * v;
    ob[(size_t)co * (HO * WO)] = v;
  }
}

// ---------- adaptive avg pool 250x250 -> 3x3 ----------
__global__ __launch_bounds__(256) void pool_k(const float* __restrict__ g,
                                              float* __restrict__ poolo) {
  int blk = blockIdx.x;
  int bc = blk / 9;
  int ij = blk % 9;
  int i = ij / 3, j = ij % 3;
  const int r0s[3] = {0, 83, 166}, r1s[3] = {84, 167, 250};
  int r0 = r0s[i], r1 = r1s[i], c0 = r0s[j], c1 = r1s[j];
  const float* p = g + (size_t)bc * 62500;
  int nc = c1 - c0;
  int tot = (r1 - r0) * nc;
  float s = 0.f;
  for (int e = threadIdx.x; e < tot; e += 256) {
    int rr = e / nc, cc = e % nc;
    s += p[(r0 + rr) * 250 + c0 + cc];
  }
  for (int off = 32; off > 0; off >>= 1) s += __shfl_down(s, off, 64);
  __shared__ float red[4];
  int lane = threadIdx.x & 63, wid = threadIdx.x >> 6;
  if (lane == 0) red[wid] = s;
  __syncthreads();
  if (threadIdx.x == 0) poolo[blk] = (red[0] + red[1] + red[2] + red[3]) / (float)tot;
}

// ---------- kernel_P ----------
__global__ __launch_bounds__(256) void kp_k(const float* __restrict__ poolv,
                                            const float* __restrict__ w4,
                                            const float* __restrict__ b4,
                                            float* __restrict__ kp) {
  int b = blockIdx.x;
  int t = threadIdx.x;
  __shared__ float vals[144];
  __shared__ float w_[256];
  __shared__ float bb[16];
  if (t < 256) w_[t] = w4[t];
  if (t < 16) bb[t] = b4[t];
  __syncthreads();
  if (t < 144) {
    int c = t / 9, ij = t % 9;
    float a = bb[c];
    for (int k = 0; k < 16; k++)
      a = fmaf(w_[c * 16 + k], poolv[b * 144 + k * 9 + ij], a);
    vals[t] = expf(a);
  }
  __syncthreads();
  if (t < 144) {
    int c = t / 9;
    float m = 0.f;
#pragma unroll
    for (int q = 0; q < 9; q++) m += vals[c * 9 + q];
    kp[b * 144 + t] = vals[t] - m * (1.0f / 9.0f);
  }
}

// ---------- pad (edge) + split into 3 bf16 planes [64][320][320] ----------
__global__ __launch_bounds__(256) void padsplit_k(const float* __restrict__ cls,
                                                  u16* __restrict__ p0) {
  size_t idx = (size_t)blockIdx.x * 256 + threadIdx.x;
  if (idx >= (size_t)IMGS * 102400) return;
  int n = (int)(idx % 320);
  size_t rest = idx / 320;
  int m = (int)(rest % 320);
  size_t img = rest / 320;
  float val = 0.f;
  if (m < 298 && n < 298) {
    int sy = min(max(m - 21, 0), 255);
    int sx = min(max(n - 21, 0), 255);
    val = cls[img * 65536 + (size_t)sy * 256 + sx];
  }
  u16 h, mm, ll;
  split3(val, h, mm, ll);
  p0[idx] = h;
  p0[6553600u + idx] = mm;
  p0[13107200u + idx] = ll;
}

// ---------- Kf (half-plane v<150) ----------
__global__ __launch_bounds__(256) void kf_k(const float* __restrict__ ker,
                                            const float2* __restrict__ tw,
                                            float2* __restrict__ Kf) {
  int b = blockIdx.y;
  __shared__ float ks[441];
  int t = threadIdx.x;
  for (int i = t; i < 441; i += 256) ks[i] = ker[b * 441 + i];
  __syncthreads();
  int uv = blockIdx.x * 256 + t;
  if (uv >= 298 * 150) return;
  int u = uv / 150, v = uv % 150;
  int tu = (10 * u) % 298, tv = (10 * v) % 298;
  int t_i = (2 * 298 - tu - tv) % 298;
  float ar = 0.f, ai = 0.f;
  for (int i = 0; i < 21; i++) {
    int tt = t_i;
#pragma unroll
    for (int j = 0; j < 21; j++) {
      float kv = ks[i * 21 + j];
      float2 wv = tw[tt];
      ar = fmaf(kv, wv.x, ar);
      ai = fmaf(kv, wv.y, ai);
      tt += v; if (tt >= 298) tt -= 298;
    }
    t_i += u; if (t_i >= 298) t_i -= 298;
  }
  Kf[(size_t)b * (298 * 150) + uv] = make_float2(ar, ai);
}

// ---------- Wiener multiply (reads G fp32) + split -> Gsplit planes ----------
__global__ __launch_bounds__(256) void gmul_split_k(const float* __restrict__ Gf,
                                                    const float2* __restrict__ Kf,
                                                    const float* __restrict__ kp,
                                                    const float2* __restrict__ tw,
                                                    u32* __restrict__ g0) {
  int img = blockIdx.y;
  int b = img >> 4;
  __shared__ float kps[9];
  if (threadIdx.x < 9) kps[threadIdx.x] = kp[img * 9 + threadIdx.x];
  __syncthreads();
  int idx = blockIdx.x * 256 + threadIdx.x;
  if (idx >= 320 * 160) return;
  int u = idx / 160, v = idx % 160;
  float gr = 0.f, gi = 0.f;
  if (u < 298 && v < 150) {
    const float* gp = Gf + (size_t)img * 102400 + (size_t)u * 320 + 2 * v;
    float fr = gp[0], fi = gp[1];
    int um = (u == 0) ? 0 : (298 - u);
    int vm = (v == 0) ? 0 : (298 - v);
    int iu[3] = {um, 0, u}, jv[3] = {vm, 0, v};
    float pr = 0.f, pi = 0.f;
#pragma unroll
    for (int i = 0; i < 3; i++) {
#pragma unroll
      for (int j = 0; j < 3; j++) {
        int tt = iu[i] + jv[j];
        if (tt >= 298) tt -= 298;
        float kv = kps[i * 3 + j];
        float2 wv = tw[tt];
        pr = fmaf(kv, wv.x, pr);
        pi = fmaf(kv, wv.y, pi);
      }
    }
    float2 kf = Kf[(size_t)b * (298 * 150) + (size_t)u * 150 + v];
    float denom = kf.x * kf.x + kf.y * kf.y + pr * pr + pi * pi;
    float inv = 1.0f / denom;
    float ir = kf.x * inv, ii = -kf.y * inv;
    gr = ir * fr - ii * fi;
    gi = ir * fi + ii * fr;
  }
  u16 hr, mr, lr, hi2, mi2, li2;
  split3(gr, hr, mr, lr);
  split3(gi, hi2, mi2, li2);
  size_t o = (size_t)img * 51200 + (size_t)u * 160 + v;
  g0[o]             = (u32)hr | ((u32)hi2 << 16);
  g0[3276800u + o]  = (u32)mr | ((u32)mi2 << 16);
  g0[6553600u + o]  = (u32)lr | ((u32)li2 << 16);
}

// ---------- bf16x3-split MFMA GEMM ----------
// BM=128, BN=64, BK=32, 4 waves (2M x 2N), wave tile 64x32, frag 16x16x32.
// LDS: A [3][128][40] u16 (pitch 80B), B [3][64][40] u16.
#define APITCH 40
#define ALDSP (128 * APITCH)
#define BLDSP (64 * APITCH)

template <int V>
__global__ __launch_bounds__(256, 3) void gemmV(
    const u16* __restrict__ Ab, const u16* __restrict__ Bb, const u16* __restrict__ Bb2,
    float* __restrict__ oF,
    u16* __restrict__ o0, u16* __restrict__ o1, u16* __restrict__ o2,
    int KT) {
  __shared__ u16 lds[3 * ALDSP + 3 * BLDSP];
  u16* Al = lds;
  u16* Bl = lds + 3 * ALDSP;
  const int tid = threadIdx.x;
  const int img = blockIdx.z;
  const int m0 = blockIdx.y * 128;
  const int n0 = blockIdx.x * 64;
  const int lane = tid & 63;
  const int w = tid >> 6;
  const int wm = w & 1, wn = w >> 1;

  f32x4 acc[4][2];
#pragma unroll
  for (int i = 0; i < 4; i++)
#pragma unroll
    for (int j = 0; j < 2; j++) acc[i][j] = (f32x4){0.f, 0.f, 0.f, 0.f};

  for (int kt = 0; kt < KT; ++kt) {
    // ---- stage A: 3 planes x 128 rows x 32 bf16 ----
#pragma unroll
    for (int s = 0; s < 6; ++s) {
      int c = tid + s * 256;
      int p = c >> 9, rem = c & 511;
      int r = rem >> 2, q = rem & 3;
      uint4 val = make_uint4(0u, 0u, 0u, 0u);
      if constexpr (V == 1) {
        int gr = m0 + r;
        if (gr < 320)
          val = *(const uint4*)(Ab + (size_t)p * 6553600u + (size_t)img * 102400u +
                                (size_t)gr * 320 + kt * 32 + q * 8);
      } else if constexpr (V == 2) {
        int gr = m0 + r;
        if (gr < 320)
          val = *(const uint4*)(Ab + (size_t)p * 204800u + (size_t)gr * 640 + kt * 32 + q * 8);
      } else if constexpr (V == 3) {
        int gr = m0 + r + 21;
        val = *(const uint4*)(Ab + (size_t)p * 204800u + (size_t)gr * 640 + kt * 32 + q * 8);
        val.x ^= 0x80000000u; val.y ^= 0x80000000u; val.z ^= 0x80000000u; val.w ^= 0x80000000u;
      } else {
        int gr = m0 + r;
        val = *(const uint4*)(Ab + (size_t)p * 5242880u + (size_t)img * 81920u +
                              (size_t)gr * 320 + kt * 32 + q * 8);
      }
      *(uint4*)&Al[p * ALDSP + r * APITCH + q * 8] = val;
    }
    // ---- stage B: 3 planes x 64 rows x 32 bf16 (transposed [n][k]) ----
    if constexpr (V == 1 || V == 4) {
#pragma unroll
      for (int s = 0; s < 3; ++s) {
        int c = tid + s * 256;
        int p = c >> 8, rem = c & 255;
        int rr = rem >> 2, q = rem & 3;
        uint4 val;
        if constexpr (V == 1) {
          int np = n0 + rr;
          int v = np >> 1;
          const u16* src = (np & 1) ? Bb2 : Bb;
          val = *(const uint4*)(src + (size_t)p * 102400u + (size_t)v * 320 + kt * 32 + q * 8);
        } else {
          val = *(const uint4*)(Bb + (size_t)p * 81920u + (size_t)(n0 + rr) * 320 + kt * 32 + q * 8);
        }
        *(uint4*)&Bl[p * BLDSP + rr * APITCH + q * 8] = val;
      }
    } else {
      // complex 2x2 expansion from [k][v] (r,i) pairs
      u32* Blu = (u32*)Bl;
#pragma unroll
      for (int s = 0; s < 6; ++s) {
        int i = tid + s * 256;
        int vv = i & 31, kk = (i >> 5) & 15, p = i >> 9;
        int v = (n0 >> 1) + vv;
        int kg = kt * 16 + kk;
        u32 ri = *(const u32*)(Bb + (size_t)p * 6553600u + (size_t)img * 102400u +
                               (size_t)kg * 320 + 2 * v);
        u32 r_ = ri & 0xffffu, i_ = ri >> 16;
        u32 w0 = r_ | ((i_ ^ 0x8000u) << 16);   // row 2v:   ( r, -i)
        u32 w1 = i_ | (r_ << 16);               // row 2v+1: ( i,  r)
        int base = p * (BLDSP / 2) + vv * APITCH + kk;
        Blu[base] = w0;
        Blu[base + (APITCH / 2)] = w1;
      }
    }
    __syncthreads();

    // ---- fragments & MFMA ----
    bf16x8 af[4][3], bfv[2][3];
    const int arow = wm * 64 + (lane & 15);
    const int c8 = (lane >> 4) * 8;
#pragma unroll
    for (int fm = 0; fm < 4; ++fm)
#pragma unroll
      for (int p = 0; p < 3; ++p)
        af[fm][p] = *(const bf16x8*)&Al[p * ALDSP + (arow + fm * 16) * APITCH + c8];
    const int brow = wn * 32 + (lane & 15);
#pragma unroll
    for (int fn = 0; fn < 2; ++fn)
#pragma unroll
      for (int p = 0; p < 3; ++p)
        bfv[fn][p] = *(const bf16x8*)&Bl[p * BLDSP + (brow + fn * 16) * APITCH + c8];
#pragma unroll
    for (int fm = 0; fm < 4; ++fm)
#pragma unroll
      for (int fn = 0; fn < 2; ++fn) {
        f32x4 a = acc[fm][fn];
        a = __builtin_amdgcn_mfma_f32_16x16x32_bf16(af[fm][2], bfv[fn][0], a, 0, 0, 0);
        a = __builtin_amdgcn_mfma_f32_16x16x32_bf16(af[fm][0], bfv[fn][2], a, 0, 0, 0);
        a = __builtin_amdgcn_mfma_f32_16x16x32_bf16(af[fm][1], bfv[fn][1], a, 0, 0, 0);
        a = __builtin_amdgcn_mfma_f32_16x16x32_bf16(af[fm][1], bfv[fn][0], a, 0, 0, 0);
        a = __builtin_amdgcn_mfma_f32_16x16x32_bf16(af[fm][0], bfv[fn][1], a, 0, 0, 0);
        a = __builtin_amdgcn_mfma_f32_16x16x32_bf16(af[fm][0], bfv[fn][0], a, 0, 0, 0);
        acc[fm][fn] = a;
      }
    __syncthreads();
  }

  // ---- epilogue ----
  const int rowL = (lane >> 4) * 4;
  const int colL = lane & 15;
#pragma unroll
  for (int fm = 0; fm < 4; ++fm)
#pragma unroll
    for (int fn = 0; fn < 2; ++fn) {
      int gcol = n0 + wn * 32 + fn * 16 + colL;
#pragma unroll
      for (int i = 0; i < 4; ++i) {
        int grow = m0 + wm * 64 + fm * 16 + rowL + i;
        float v = acc[fm][fn][i];
        if constexpr (V == 1) {
          if (grow < 320) {
            u16 h = 0, mm = 0, ll = 0;
            if (gcol < 300) split3(v, h, mm, ll);
            size_t off = (size_t)img * 102400u + (size_t)grow * 320 + gcol;
            o0[off] = h; o1[off] = mm; o2[off] = ll;
          }
        } else if constexpr (V == 2) {
          if (grow < 320)
            oF[(size_t)img * 102400u + (size_t)grow * 320 + gcol] = v;
        } else if constexpr (V == 3) {
          u16 h = 0, mm = 0, ll = 0;
          if (gcol < 300) split3(v, h, mm, ll);
          size_t off = (size_t)img * 81920u + (size_t)grow * 320 + gcol;
          o0[off] = h; o1[off] = mm; o2[off] = ll;
        } else {
          oF[(size_t)img * 65536u + (size_t)grow * 256 + gcol] = v * (1.0f / 88804.0f);
        }
      }
    }
}

// ---------- 1x1 expand conv ----------
__global__ __launch_bounds__(256) void expand_k(const float* __restrict__ D,
                                                const float* __restrict__ w,
                                                const float* __restrict__ bias,
                                                float* __restrict__ out) {
  __shared__ float ws_[1024];
  __shared__ float bs_[64];
  int t = threadIdx.x;
  for (int i = t; i < 1024; i += 256) ws_[i] = w[i];
  if (t < 64) bs_[t] = bias[t];
  __syncthreads();
  int b = blockIdx.y;
  int hw = blockIdx.x * 256 + t;
  const float* Db = D + (size_t)b * 16 * DSLAB + hw;
  float d[16];
#pragma unroll
  for (int c = 0; c < 16; c++) d[c] = Db[(size_t)c * DSLAB];
  float* ob = out + ((size_t)b * 64) * 65536 + hw;
  for (int o = 0; o < 64; o++) {
    float a = bs_[o];
#pragma unroll
    for (int c = 0; c < 16; c++) a = fmaf(ws_[o * 16 + c], d[c], a);
    ob[(size_t)o * 65536] = a;
  }
}

extern "C" void kernel_launch(void* const* d_in, const int* in_sizes, int n_in,
                              void* d_out, int out_size, void* d_ws, size_t ws_size,
                              hipStream_t stream) {
  (void)in_sizes; (void)n_in; (void)out_size; (void)ws_size;
  const float* x        = (const float*)d_in[0];
  const float* kernel   = (const float*)d_in[1];
  const float* w_reduce = (const float*)d_in[2];
  const float* b_reduce = (const float*)d_in[3];
  const float* w_g1     = (const float*)d_in[4];
  const float* b_g1     = (const float*)d_in[5];
  const float* w_g2     = (const float*)d_in[6];
  const float* b_g2     = (const float*)d_in[7];
  const float* w_g3     = (const float*)d_in[8];
  const float* b_g3     = (const float*)d_in[9];
  const float* w_g4     = (const float*)d_in[10];
  const float* b_g4     = (const float*)d_in[11];
  const float* w_expand = (const float*)d_in[12];
  const float* b_expand = (const float*)d_in[13];
  float* out = (float*)d_out;

  // ---- workspace layout (float offsets); aliasing is time-disjoint ----
  float* ws_f = (float*)d_ws;
  float* cls  = ws_f;                          // [0 .. 4,194,304)   dead after padsplit
  float* gA   = ws_f + 4194304;                // conv ping
  float* gB   = ws_f + 8323328;                // conv pong
  u16*  T1s   = (u16*)ws_f;                    // [0 .. 9,830,400)f  P1 out (3 planes)
  u16*  padsp = (u16*)(ws_f + 12452352);       // [12.45M .. 22.28M)f  pad splits
  float* Gf   = ws_f + 12452352;               // over padsp after P1 (6.55Mf)
  u16*  Gs    = (u16*)ws_f;                    // over T1s after P2 (9.83Mf)
  u16*  Es    = (u16*)(ws_f + 12452352);       // over Gf after gmul (7.86Mf)
  float* Df   = ws_f;                          // over Gs after P3 (4.19Mf)
  float2* tw  = (float2*)(ws_f + 22282752);
  u16*  Wr    = (u16*)(ws_f + 22283392);       // 3 x 102400 u16
  u16*  Wi    = (u16*)(ws_f + 22436992);
  u32*  Wri   = (u32*)(ws_f + 22590592);       // 3 x 102400 u32
  u16*  B4t   = (u16*)(ws_f + 22897792);       // 3 x 81920 u16
  float2* Kf2 = (float2*)(ws_f + 23020672);
  float* poolb= ws_f + 23378272;
  float* kpb  = ws_f + 23378848;

  // ---- static tables ----
  twtab_k<<<dim3(2), 256, 0, stream>>>(tw);
  wsplit_k<<<dim3(400), 256, 0, stream>>>(Wr, Wi, Wri);
  b4t_k<<<dim3(160), 256, 0, stream>>>(B4t);

  // ---- conv chain ----
  reduce_k<<<dim3(256, NB), 256, 0, stream>>>(x, w_reduce, b_reduce, cls);
  conv3_k<<<dim3((254 * 254 + 255) / 256, NB), 256, 0, stream>>>(cls, w_g1, b_g1, gA, 256, 256, 1);
  conv3_k<<<dim3((252 * 252 + 255) / 256, NB), 256, 0, stream>>>(gA, w_g2, b_g2, gB, 254, 254, 1);
  conv3_k<<<dim3((250 * 250 + 255) / 256, NB), 256, 0, stream>>>(gB, w_g3, b_g3, gA, 252, 252, 0);
  pool_k<<<dim3(NB * 16 * 9), 256, 0, stream>>>(gA, poolb);
  kp_k<<<dim3(NB), 256, 0, stream>>>(poolb, w_g4, b_g4, kpb);

  // ---- pad + split, Kf ----
  padsplit_k<<<dim3(25600), 256, 0, stream>>>(cls, padsp);
  kf_k<<<dim3((298 * 150 + 255) / 256, NB), 256, 0, stream>>>(kernel, tw, Kf2);

  // ---- P1: T1 = pad @ W (real x complex) -> T1 splits ----
  gemmV<1><<<dim3(5, 3, IMGS), 256, 0, stream>>>(padsp, Wr, Wi, nullptr,
                                                 T1s, T1s + 6553600u, T1s + 13107200u, 10);
  // ---- P2: G = W @ T1 (complex) -> G fp32 ----
  gemmV<2><<<dim3(5, 3, IMGS), 256, 0, stream>>>((const u16*)Wri, T1s, nullptr, Gf,
                                                 nullptr, nullptr, nullptr, 20);
  // ---- Wiener + split ----
  gmul_split_k<<<dim3(200, IMGS), 256, 0, stream>>>(Gf, Kf2, kpb, tw, (u32*)Gs);
  // ---- P3: E = conj(W)[21:277] @ G (complex) -> E splits ----
  gemmV<3><<<dim3(5, 2, IMGS), 256, 0, stream>>>((const u16*)Wri, Gs, nullptr, nullptr,
                                                 Es, Es + 5242880u, Es + 10485760u, 20);
  // ---- P4: D = E_f @ B4t^T (real, folded crop + 1/N^2) ----
  gemmV<4><<<dim3(4, 2, IMGS), 256, 0, stream>>>(Es, B4t, nullptr, Df,
                                                 nullptr, nullptr, nullptr, 10);
  // ---- expand ----
  expand_k<<<dim3(256, NB), 256, 0, stream>>>(Df, w_expand, b_expand, out);
}

// Round 7
// 425.130 us; speedup vs baseline: 2.5275x; 1.2818x over previous
//
#include <hip/hip_runtime.h>
#include <math.h>

typedef unsigned short u16;
typedef unsigned int   u32;
typedef _Float16 f16x8 __attribute__((ext_vector_type(8)));
typedef __attribute__((ext_vector_type(4))) float f32x4;

#define NB    4
#define IMGS  64
#define DSLAB (256*256)
#define TWO_PI 6.283185307179586f

// Scale plan (pipeline linear in pad; total compensated exactly in P4):
//   Wx1 *= 1/64   -> T1' = T1/64, F' = F/64 (fp32)
//   gmul *= 1/64  -> G'  = G/4096   (raw |G| up to ~1e6-1e7; G' < ~2.5e3 << 65504)
//   P3   *= 1/16  -> E'' = E/65536  (raw |E| up to ~1e7; E'' < ~200)
//   P4   *= 65536/88804  (exact fp32)
#define S_WX1  0.015625f
#define S_GMUL 0.015625f
#define S_P3   0.0625f
#define S_P4   (65536.0f / 88804.0f)

// ---------- fp16 2-way split ----------
__device__ __forceinline__ void split2(float x, u16& h, u16& l) {
  _Float16 hh = (_Float16)x;
  float r = x - (float)hh;
  _Float16 ll = (_Float16)r;
  h = *(u16*)&hh; l = *(u16*)&ll;
}

// ---------- twiddle table tw[t] = exp(-2*pi*i*t/298) (fp32, for kf/gmul) ----
__global__ __launch_bounds__(256) void twtab_k(float2* __restrict__ tw) {
  int t = blockIdx.x * 256 + threadIdx.x;
  if (t >= 298) return;
  float ang = (-TWO_PI / 298.0f) * (float)t;
  float s, c; sincosf(ang, &s, &c);
  tw[t] = make_float2(c, s);
}

// ---------- Wx1 [2][384][320]: row 2v = cos(phi_vn), row 2v+1 = sin(phi_vn) --
__global__ __launch_bounds__(256) void wx1_k(u16* __restrict__ W) {
  int idx = blockIdx.x * 256 + threadIdx.x;
  if (idx >= 122880) return;
  int rho = idx / 320, n = idx % 320;
  float val = 0.f;
  if (rho < 300 && n < 298) {
    int v = rho >> 1, s = rho & 1;
    int m = (v * n) % 298;
    float ph = (TWO_PI / 298.0f) * (float)m;
    float sn, cs; sincosf(ph, &sn, &cs);
    val = (s ? sn : cs) * S_WX1;
  }
  u16 h, l; split2(val, h, l);
  W[idx] = h; W[122880 + idx] = l;
}

// ---------- We [2][640][640]: row 2u = (Wr,Wi) pairs, row 2u+1 = (Wi,-Wr) ----
__global__ __launch_bounds__(256) void we_k(u16* __restrict__ W) {
  int idx = blockIdx.x * 256 + threadIdx.x;
  if (idx >= 409600) return;
  int j2 = idx / 640, k = idx % 640;
  int u = j2 >> 1, pc = j2 & 1;
  int mm = k >> 1, p = k & 1;
  float val = 0.f;
  if (u < 298 && mm < 298) {
    int m = (u * mm) % 298;
    float ph = (TWO_PI / 298.0f) * (float)m;
    float sn, cs; sincosf(ph, &sn, &cs);
    // Wr = cs, Wi = -sn
    val = (pc == 0) ? (p == 0 ? cs : -sn) : (p == 0 ? -sn : -cs);
  }
  u16 h, l; split2(val, h, l);
  W[idx] = h; W[409600 + idx] = l;
}

// ---------- B4t [2][256][320]: k'=2v+p holds fac*(re,im) of W[v][n+21] -------
__global__ __launch_bounds__(256) void b4t_k(u16* __restrict__ b4) {
  int idx = blockIdx.x * 256 + threadIdx.x;
  if (idx >= 40960) return;
  int v = idx / 256, n = idx % 256;
  float re = 0.f, im = 0.f;
  if (v < 150) {
    int m = (v * (n + 21)) % 298;
    float ang = (-TWO_PI / 298.0f) * (float)m;
    float s, c; sincosf(ang, &s, &c);
    float fac = (v >= 1 && v < 149) ? 2.f : 1.f;
    re = fac * c; im = fac * s;
  }
  u16 hr, lr, hi, li;
  split2(re, hr, lr); split2(im, hi, li);
  size_t o = (size_t)n * 320 + 2 * v;
  b4[o] = hr; b4[o + 1] = hi;
  b4[81920 + o] = lr; b4[81920 + o + 1] = li;
}

// ---------- 1x1 reduce conv ----------
__global__ __launch_bounds__(256) void reduce_k(const float* __restrict__ x,
                                                const float* __restrict__ w,
                                                const float* __restrict__ bias,
                                                float* __restrict__ cls) {
  __shared__ float ws_[1024];
  __shared__ float bs_[16];
  int t = threadIdx.x;
  for (int i = t; i < 1024; i += 256) ws_[i] = w[i];
  if (t < 16) bs_[t] = bias[t];
  __syncthreads();
  int b = blockIdx.y;
  int hw = blockIdx.x * 256 + t;
  const float* xb = x + ((size_t)b * 64) * 65536 + hw;
  float acc[16];
#pragma unroll
  for (int c = 0; c < 16; c++) acc[c] = bs_[c];
  for (int k = 0; k < 64; k++) {
    float xv = xb[(size_t)k * 65536];
#pragma unroll
    for (int c = 0; c < 16; c++) acc[c] = fmaf(ws_[c * 64 + k], xv, acc[c]);
  }
  float* ob = cls + ((size_t)b * 16) * 65536 + hw;
#pragma unroll
  for (int c = 0; c < 16; c++) ob[(size_t)c * 65536] = acc[c];
}

// ---------- 3x3 VALID conv ----------
__global__ __launch_bounds__(256) void conv3_k(const float* __restrict__ in,
                                               const float* __restrict__ w,
                                               const float* __restrict__ bias,
                                               float* __restrict__ out,
                                               int HI, int WI, int relu) {
  __shared__ float ws_[2304];
  __shared__ float bs_[16];
  int t = threadIdx.x;
  for (int i = t; i < 2304; i += 256) ws_[i] = w[i];
  if (t < 16) bs_[t] = bias[t];
  __syncthreads();
  int HO = HI - 2, WO = WI - 2;
  int b = blockIdx.y;
  int idx = blockIdx.x * 256 + t;
  if (idx >= HO * WO) return;
  int y = idx / WO, xx = idx % WO;
  const float* ib = in + ((size_t)b * 16) * (size_t)(HI * WI);
  float acc[16];
#pragma unroll
  for (int c = 0; c < 16; c++) acc[c] = bs_[c];
  for (int ci = 0; ci < 16; ci++) {
    const float* p = ib + (size_t)ci * (HI * WI) + (size_t)y * WI + xx;
#pragma unroll
    for (int dy = 0; dy < 3; dy++) {
#pragma unroll
      for (int dx = 0; dx < 3; dx++) {
        float v = p[dy * WI + dx];
        int widx = ci * 9 + dy * 3 + dx;
#pragma unroll
        for (int co = 0; co < 16; co++)
          acc[co] = fmaf(ws_[co * 144 + widx], v, acc[co]);
      }
    }
  }
  float* ob = out + ((size_t)b * 16) * (size_t)(HO * WO) + (size_t)y * WO + xx;
#pragma unroll
  for (int co = 0; co < 16; co++) {
    float v = acc[co];
    if (relu) v = v > 0.f ? v : 0.1f * v;
    ob[(size_t)co * (HO * WO)] = v;
  }
}

// ---------- adaptive avg pool 250x250 -> 3x3 ----------
__global__ __launch_bounds__(256) void pool_k(const float* __restrict__ g,
                                              float* __restrict__ poolo) {
  int blk = blockIdx.x;
  int bc = blk / 9;
  int ij = blk % 9;
  int i = ij / 3, j = ij % 3;
  const int r0s[3] = {0, 83, 166}, r1s[3] = {84, 167, 250};
  int r0 = r0s[i], r1 = r1s[i], c0 = r0s[j], c1 = r1s[j];
  const float* p = g + (size_t)bc * 62500;
  int nc = c1 - c0;
  int tot = (r1 - r0) * nc;
  float s = 0.f;
  for (int e = threadIdx.x; e < tot; e += 256) {
    int rr = e / nc, cc = e % nc;
    s += p[(r0 + rr) * 250 + c0 + cc];
  }
  for (int off = 32; off > 0; off >>= 1) s += __shfl_down(s, off, 64);
  __shared__ float red[4];
  int lane = threadIdx.x & 63, wid = threadIdx.x >> 6;
  if (lane == 0) red[wid] = s;
  __syncthreads();
  if (threadIdx.x == 0) poolo[blk] = (red[0] + red[1] + red[2] + red[3]) / (float)tot;
}

// ---------- kernel_P ----------
__global__ __launch_bounds__(256) void kp_k(const float* __restrict__ poolv,
                                            const float* __restrict__ w4,
                                            const float* __restrict__ b4,
                                            float* __restrict__ kp) {
  int b = blockIdx.x;
  int t = threadIdx.x;
  __shared__ float vals[144];
  __shared__ float w_[256];
  __shared__ float bb[16];
  if (t < 256) w_[t] = w4[t];
  if (t < 16) bb[t] = b4[t];
  __syncthreads();
  if (t < 144) {
    int c = t / 9, ij = t % 9;
    float a = bb[c];
    for (int k = 0; k < 16; k++)
      a = fmaf(w_[c * 16 + k], poolv[b * 144 + k * 9 + ij], a);
    vals[t] = expf(a);
  }
  __syncthreads();
  if (t < 144) {
    int c = t / 9;
    float m = 0.f;
#pragma unroll
    for (int q = 0; q < 9; q++) m += vals[c * 9 + q];
    kp[b * 144 + t] = vals[t] - m * (1.0f / 9.0f);
  }
}

// ---------- pad (edge) + split2 into [2][64][384][320] fp16 ----------
__global__ __launch_bounds__(256) void padsplit_k(const float* __restrict__ cls,
                                                  u16* __restrict__ p0) {
  size_t idx = (size_t)blockIdx.x * 256 + threadIdx.x;
  if (idx >= 7864320u) return;
  int n = (int)(idx % 320);
  size_t rest = idx / 320;
  int m = (int)(rest % 384);
  size_t img = rest / 384;
  float val = 0.f;
  if (m < 298 && n < 298) {
    int sy = min(max(m - 21, 0), 255);
    int sx = min(max(n - 21, 0), 255);
    val = cls[img * 65536 + (size_t)sy * 256 + sx];
  }
  u16 h, l; split2(val, h, l);
  p0[idx] = h;
  p0[7864320u + idx] = l;
}

// ---------- Kf (half-plane v<150) ----------
__global__ __launch_bounds__(256) void kf_k(const float* __restrict__ ker,
                                            const float2* __restrict__ tw,
                                            float2* __restrict__ Kf) {
  int b = blockIdx.y;
  __shared__ float ks[441];
  int t = threadIdx.x;
  for (int i = t; i < 441; i += 256) ks[i] = ker[b * 441 + i];
  __syncthreads();
  int uv = blockIdx.x * 256 + t;
  if (uv >= 298 * 150) return;
  int u = uv / 150, v = uv % 150;
  int tu = (10 * u) % 298, tv = (10 * v) % 298;
  int t_i = (2 * 298 - tu - tv) % 298;
  float ar = 0.f, ai = 0.f;
  for (int i = 0; i < 21; i++) {
    int tt = t_i;
#pragma unroll
    for (int j = 0; j < 21; j++) {
      float kv = ks[i * 21 + j];
      float2 wv = tw[tt];
      ar = fmaf(kv, wv.x, ar);
      ai = fmaf(kv, wv.y, ai);
      tt += v; if (tt >= 298) tt -= 298;
    }
    t_i += u; if (t_i >= 298) t_i -= 298;
  }
  Kf[(size_t)b * (298 * 150) + uv] = make_float2(ar, ai);
}

// ---------- Wiener on Gt[v][u] fp32 -> Ge [2][64][384][640] fp16 expanded ----
// Ge row 2v = (Gr', Gi') u-pairs; row 2v+1 = (Gi', -Gr').  Output scaled 1/64.
__global__ __launch_bounds__(256) void gmul_k(const float* __restrict__ Gt,
                                              const float2* __restrict__ Kf,
                                              const float* __restrict__ kp,
                                              const float2* __restrict__ tw,
                                              u32* __restrict__ Geu) {
  int img = blockIdx.y;
  int b = img >> 4;
  __shared__ float kps[9];
  if (threadIdx.x < 9) kps[threadIdx.x] = kp[img * 9 + threadIdx.x];
  __syncthreads();
  int idx = blockIdx.x * 256 + threadIdx.x;
  if (idx >= 192 * 320) return;
  int u = idx % 320, v = idx / 320;
  float gr = 0.f, gi = 0.f;
  if (v < 150 && u < 298) {
    const float* gp = Gt + (size_t)img * 102400 + (size_t)v * 640 + 2 * u;
    float fr = gp[0], fi = gp[1];
    int um = (u == 0) ? 0 : (298 - u);
    int vm = (v == 0) ? 0 : (298 - v);
    int iu[3] = {um, 0, u}, jv[3] = {vm, 0, v};
    float pr = 0.f, pi = 0.f;
#pragma unroll
    for (int i = 0; i < 3; i++) {
#pragma unroll
      for (int j = 0; j < 3; j++) {
        int tt = iu[i] + jv[j];
        if (tt >= 298) tt -= 298;
        float kv = kps[i * 3 + j];
        float2 wv = tw[tt];
        pr = fmaf(kv, wv.x, pr);
        pi = fmaf(kv, wv.y, pi);
      }
    }
    float2 kf = Kf[(size_t)b * 44700 + (size_t)u * 150 + v];
    float denom = kf.x * kf.x + kf.y * kf.y + pr * pr + pi * pi;
    float inv = 1.0f / denom;
    float ir = kf.x * inv, ii = -kf.y * inv;
    gr = (ir * fr - ii * fi) * S_GMUL;
    gi = (ir * fi + ii * fr) * S_GMUL;
  }
  u16 ghr, glr, ghi, gli;
  split2(gr, ghr, glr); split2(gi, ghi, gli);
  size_t base = (size_t)img * 122880 + (size_t)(2 * v) * 320 + u;
  Geu[base]            = (u32)ghr | ((u32)ghi << 16);
  Geu[7864320u + base] = (u32)glr | ((u32)gli << 16);
  size_t base1 = base + 320;
  Geu[base1]            = (u32)ghi | ((u32)(ghr ^ 0x8000u) << 16);
  Geu[7864320u + base1] = (u32)gli | ((u32)(glr ^ 0x8000u) << 16);
}

// ---------- unified fp16-split MFMA GEMM ----------
// BM=BN=128, BK=32, 4 waves (2x2), wave tile 64x64, 16x16x32 f16 frags.
// Straight-copy staging for A and B^T (both [row][K] layouts).
#define LPITCH 40
#define ALSZ (128 * LPITCH)

template <int V>
__global__ __launch_bounds__(256, 3) void gemmF(
    const u16* __restrict__ Asrc, const u16* __restrict__ Bsrc,
    float* __restrict__ oF, u16* __restrict__ o0, int KT) {
  __shared__ u16 lds[4 * ALSZ];
  u16* Al = lds;
  u16* Bl = lds + 2 * ALSZ;
  const int tid = threadIdx.x;
  const int img = blockIdx.z;
  const int m0 = blockIdx.y * 128;
  const int n0 = blockIdx.x * 128;
  const int lane = tid & 63;
  const int w = tid >> 6;
  const int wm = w & 1, wn = w >> 1;

  f32x4 acc[4][4];
#pragma unroll
  for (int i = 0; i < 4; i++)
#pragma unroll
    for (int j = 0; j < 4; j++) acc[i][j] = (f32x4){0.f, 0.f, 0.f, 0.f};

  for (int kt = 0; kt < KT; ++kt) {
    // ---- stage A: 2 planes x 128 rows x 32 f16 ----
#pragma unroll
    for (int s = 0; s < 4; ++s) {
      int c = tid + s * 256;
      int p = c >> 9, rem = c & 511;
      int r = rem >> 2, q = rem & 3;
      uint4 val = make_uint4(0u, 0u, 0u, 0u);
      if constexpr (V == 1) {
        val = *(const uint4*)(Asrc + (size_t)p * 122880u + (size_t)(m0 + r) * 320 + kt * 32 + q * 8);
      } else if constexpr (V == 2) {
        int gr = m0 + r;
        if (gr < 192)
          val = *(const uint4*)(Asrc + (size_t)p * 7864320u + (size_t)img * 122880u +
                                (size_t)gr * 640 + kt * 32 + q * 8);
      } else if constexpr (V == 3) {
        val = *(const uint4*)(Asrc + (size_t)p * 409600u + (size_t)(2 * (m0 + r + 21)) * 640 +
                              kt * 32 + q * 8);
      } else {
        val = *(const uint4*)(Asrc + (size_t)p * 5242880u + (size_t)img * 81920u +
                              (size_t)(m0 + r) * 320 + kt * 32 + q * 8);
      }
      *(uint4*)&Al[p * ALSZ + r * LPITCH + q * 8] = val;
    }
    // ---- stage B^T: 2 planes x 128 rows x 32 f16 ----
#pragma unroll
    for (int s = 0; s < 4; ++s) {
      int c = tid + s * 256;
      int p = c >> 9, rem = c & 511;
      int rr = rem >> 2, q = rem & 3;
      uint4 val;
      if constexpr (V == 1) {
        val = *(const uint4*)(Bsrc + (size_t)p * 7864320u + (size_t)img * 122880u +
                              (size_t)(n0 + rr) * 320 + kt * 32 + q * 8);
      } else if constexpr (V == 2) {
        val = *(const uint4*)(Bsrc + (size_t)p * 409600u + (size_t)(n0 + rr) * 640 + kt * 32 + q * 8);
      } else if constexpr (V == 3) {
        val = *(const uint4*)(Bsrc + (size_t)p * 15728640u + (size_t)img * 245760u +
                              (size_t)(n0 + rr) * 640 + kt * 32 + q * 8);
      } else {
        val = *(const uint4*)(Bsrc + (size_t)p * 81920u + (size_t)(n0 + rr) * 320 + kt * 32 + q * 8);
      }
      *(uint4*)&Bl[p * ALSZ + rr * LPITCH + q * 8] = val;
    }
    __syncthreads();

    // ---- fragments ----
    f16x8 af[4][2], bf[4][2];
    const int arow = wm * 64 + (lane & 15);
    const int brow = wn * 64 + (lane & 15);
    const int c8 = (lane >> 4) * 8;
#pragma unroll
    for (int fm = 0; fm < 4; ++fm)
#pragma unroll
      for (int p = 0; p < 2; ++p)
        af[fm][p] = *(const f16x8*)&Al[p * ALSZ + (arow + fm * 16) * LPITCH + c8];
#pragma unroll
    for (int fn = 0; fn < 4; ++fn)
#pragma unroll
      for (int p = 0; p < 2; ++p)
        bf[fn][p] = *(const f16x8*)&Bl[p * ALSZ + (brow + fn * 16) * LPITCH + c8];
    // ---- 3-product fp32-emulating MFMA (hl + lh + hh) ----
#pragma unroll
    for (int fm = 0; fm < 4; ++fm)
#pragma unroll
      for (int fn = 0; fn < 4; ++fn) {
        f32x4 a = acc[fm][fn];
        a = __builtin_amdgcn_mfma_f32_16x16x32_f16(af[fm][1], bf[fn][0], a, 0, 0, 0);
        a = __builtin_amdgcn_mfma_f32_16x16x32_f16(af[fm][0], bf[fn][1], a, 0, 0, 0);
        a = __builtin_amdgcn_mfma_f32_16x16x32_f16(af[fm][0], bf[fn][0], a, 0, 0, 0);
        acc[fm][fn] = a;
      }
    __syncthreads();
  }

  // ---- epilogue ----
  const int rowL = (lane >> 4) * 4;
  const int colL = lane & 15;
#pragma unroll
  for (int fm = 0; fm < 4; ++fm)
#pragma unroll
    for (int fn = 0; fn < 4; ++fn) {
      int gcol = n0 + wn * 64 + fn * 16 + colL;
      int rbase = m0 + wm * 64 + fm * 16 + rowL;
      if constexpr (V == 1) {
        // rows rho -> T1e[v=rho>>1][2*mcol + (rho&1)], u32-paired, 2 planes
        if (gcol < 320) {
          u32* T1u = (u32*)o0;
#pragma unroll
          for (int i = 0; i < 4; i += 2) {
            int rho = rbase + i;
            int v = rho >> 1;
            u16 h0, l0, h1, l1;
            split2(acc[fm][fn][i], h0, l0);
            split2(acc[fm][fn][i + 1], h1, l1);
            size_t off = (size_t)img * 61440u + (size_t)v * 320 + gcol;
            T1u[off] = (u32)h0 | ((u32)h1 << 16);
            T1u[3932160u + off] = (u32)l0 | ((u32)l1 << 16);
          }
        }
      } else if constexpr (V == 2) {
#pragma unroll
        for (int i = 0; i < 4; ++i) {
          int vg = rbase + i;
          if (vg < 160)
            oF[(size_t)img * 102400u + (size_t)vg * 640 + gcol] = acc[fm][fn][i];
        }
      } else if constexpr (V == 3) {
        if (gcol < 320) {
#pragma unroll
          for (int i = 0; i < 4; ++i) {
            int mg = rbase + i;
            u16 h, l;
            split2(acc[fm][fn][i] * S_P3, h, l);
            size_t off = (size_t)img * 81920u + (size_t)mg * 320 + gcol;
            o0[off] = h;
            o0[5242880u + off] = l;
          }
        }
      } else {
#pragma unroll
        for (int i = 0; i < 4; ++i) {
          int mg = rbase + i;
          oF[(size_t)img * 65536u + (size_t)mg * 256 + gcol] = acc[fm][fn][i] * S_P4;
        }
      }
    }
}

// ---------- 1x1 expand conv ----------
__global__ __launch_bounds__(256) void expand_k(const float* __restrict__ D,
                                                const float* __restrict__ w,
                                                const float* __restrict__ bias,
                                                float* __restrict__ out) {
  __shared__ float ws_[1024];
  __shared__ float bs_[64];
  int t = threadIdx.x;
  for (int i = t; i < 1024; i += 256) ws_[i] = w[i];
  if (t < 64) bs_[t] = bias[t];
  __syncthreads();
  int b = blockIdx.y;
  int hw = blockIdx.x * 256 + t;
  const float* Db = D + (size_t)b * 16 * DSLAB + hw;
  float d[16];
#pragma unroll
  for (int c = 0; c < 16; c++) d[c] = Db[(size_t)c * DSLAB];
  float* ob = out + ((size_t)b * 64) * 65536 + hw;
  for (int o = 0; o < 64; o++) {
    float a = bs_[o];
#pragma unroll
    for (int c = 0; c < 16; c++) a = fmaf(ws_[o * 16 + c], d[c], a);
    ob[(size_t)o * 65536] = a;
  }
}

extern "C" void kernel_launch(void* const* d_in, const int* in_sizes, int n_in,
                              void* d_out, int out_size, void* d_ws, size_t ws_size,
                              hipStream_t stream) {
  (void)in_sizes; (void)n_in; (void)out_size; (void)ws_size;
  const float* x        = (const float*)d_in[0];
  const float* kernel   = (const float*)d_in[1];
  const float* w_reduce = (const float*)d_in[2];
  const float* b_reduce = (const float*)d_in[3];
  const float* w_g1     = (const float*)d_in[4];
  const float* b_g1     = (const float*)d_in[5];
  const float* w_g2     = (const float*)d_in[6];
  const float* b_g2     = (const float*)d_in[7];
  const float* w_g3     = (const float*)d_in[8];
  const float* b_g3     = (const float*)d_in[9];
  const float* w_g4     = (const float*)d_in[10];
  const float* b_g4     = (const float*)d_in[11];
  const float* w_expand = (const float*)d_in[12];
  const float* b_expand = (const float*)d_in[13];
  float* out = (float*)d_out;

  // ---- workspace layout (float offsets); all aliases time-disjoint ----
  float* ws_f = (float*)d_ws;
  float* cls   = ws_f;
  float* gA    = ws_f + 4194304;
  float* gB    = ws_f + 8323328;
  u16*  padsp  = (u16*)(ws_f + 4194304);
  u16*  T1e    = (u16*)(ws_f + 12452352);
  float* Gt    = ws_f;
  u16*  Ge     = (u16*)(ws_f + 12452352);
  u16*  E2     = (u16*)ws_f;
  float* Df    = ws_f + 5242880;
  float2* tw   = (float2*)(ws_f + 28180992);
  float2* Kf2  = (float2*)(ws_f + 28182016);
  u16*  Wx1    = (u16*)(ws_f + 28540416);
  u16*  We     = (u16*)(ws_f + 28663296);
  u16*  B4t    = (u16*)(ws_f + 29072896);
  float* poolb = ws_f + 29154816;
  float* kpb   = ws_f + 29155392;

  // ---- static tables ----
  twtab_k<<<dim3(2), 256, 0, stream>>>(tw);
  wx1_k<<<dim3(480), 256, 0, stream>>>(Wx1);
  we_k<<<dim3(1600), 256, 0, stream>>>(We);
  b4t_k<<<dim3(160), 256, 0, stream>>>(B4t);

  // ---- conv chain ----
  reduce_k<<<dim3(256, NB), 256, 0, stream>>>(x, w_reduce, b_reduce, cls);
  conv3_k<<<dim3((254 * 254 + 255) / 256, NB), 256, 0, stream>>>(cls, w_g1, b_g1, gA, 256, 256, 1);
  conv3_k<<<dim3((252 * 252 + 255) / 256, NB), 256, 0, stream>>>(gA, w_g2, b_g2, gB, 254, 254, 1);
  conv3_k<<<dim3((250 * 250 + 255) / 256, NB), 256, 0, stream>>>(gB, w_g3, b_g3, gA, 252, 252, 0);
  pool_k<<<dim3(NB * 16 * 9), 256, 0, stream>>>(gA, poolb);
  kp_k<<<dim3(NB), 256, 0, stream>>>(poolb, w_g4, b_g4, kpb);

  // ---- pad + split, Kf ----
  padsplit_k<<<dim3(30720), 256, 0, stream>>>(cls, padsp);
  kf_k<<<dim3((298 * 150 + 255) / 256, NB), 256, 0, stream>>>(kernel, tw, Kf2);

  // ---- P1: T1e[v][2m+s] = Wx1 x pad^T  (M=384, N=384->320, K=320) ----
  gemmF<1><<<dim3(3, 3, IMGS), 256, 0, stream>>>(Wx1, padsp, nullptr, T1e, 10);
  // ---- P2: Gt[v][2u+pc] = T1e x We^T  (M=256->160, N=640, K=640) ----
  gemmF<2><<<dim3(5, 2, IMGS), 256, 0, stream>>>(T1e, We, Gt, nullptr, 20);
  // ---- Wiener + expand-split -> Ge (scaled 1/64) ----
  gmul_k<<<dim3(240, IMGS), 256, 0, stream>>>(Gt, Kf2, kpb, tw, (u32*)Ge);
  // ---- P3: E[m][2v+q] = We(rows 2(m+21)) x Ge^T  (M=256, N=384->320, K=640) ----
  gemmF<3><<<dim3(3, 2, IMGS), 256, 0, stream>>>(We, Ge, nullptr, E2, 20);
  // ---- P4: D = E2 x B4t^T * 65536/88804  (M=256, N=256, K=320) ----
  gemmF<4><<<dim3(2, 2, IMGS), 256, 0, stream>>>(E2, B4t, Df, nullptr, 10);
  // ---- expand ----
  expand_k<<<dim3(256, NB), 256, 0, stream>>>(Df, w_expand, b_expand, out);
}

// Round 8
// 385.886 us; speedup vs baseline: 2.7845x; 1.1017x over previous
//
#include <hip/hip_runtime.h>
#include <math.h>

typedef unsigned short u16;
typedef unsigned int   u32;
typedef _Float16 f16x8 __attribute__((ext_vector_type(8)));
typedef __attribute__((ext_vector_type(4))) float f32x4;

#define NB    4
#define IMGS  64
#define DSLAB (256*256)
#define TWO_PI 6.283185307179586f

// Scale plan (pipeline linear in pad; total compensated exactly in P4):
//   Wx1 *= 1/64   -> T1' = T1/64, F' = F/64 (fp32)
//   gmul *= 1/64  -> G'  = G/4096   (|G'| < ~2.5e3 << 65504)
//   P3   *= 1/16  -> E'' = E/65536
//   P4   *= 65536/88804  (exact fp32)
#define S_WX1  0.015625f
#define S_GMUL 0.015625f
#define S_P3   0.0625f
#define S_P4   (65536.0f / 88804.0f)

// ---------- fp16 2-way split ----------
__device__ __forceinline__ void split2(float x, u16& h, u16& l) {
  _Float16 hh = (_Float16)x;
  float r = x - (float)hh;
  _Float16 ll = (_Float16)r;
  h = *(u16*)&hh; l = *(u16*)&ll;
}
__device__ __forceinline__ u16 f2h(float x) {
  _Float16 hh = (_Float16)x;
  return *(u16*)&hh;
}

// ---------- fused static tables: tw, Wx1, We, B4t in ONE launch ----------
__global__ __launch_bounds__(256) void tables_k(float2* __restrict__ tw,
                                                u16* __restrict__ Wx1,
                                                u16* __restrict__ We,
                                                u16* __restrict__ B4t) {
  int idx = blockIdx.x * 256 + threadIdx.x;
  if (idx < 298) {
    float ang = (-TWO_PI / 298.0f) * (float)idx;
    float s, c; sincosf(ang, &s, &c);
    tw[idx] = make_float2(c, s);
  }
  if (idx < 122880) {   // Wx1 [2][384][320]: row 2v = cos, 2v+1 = sin, *S_WX1
    int rho = idx / 320, n = idx % 320;
    float val = 0.f;
    if (rho < 300 && n < 298) {
      int v = rho >> 1, s = rho & 1;
      int m = (v * n) % 298;
      float ph = (TWO_PI / 298.0f) * (float)m;
      float sn, cs; sincosf(ph, &sn, &cs);
      val = (s ? sn : cs) * S_WX1;
    }
    u16 h, l; split2(val, h, l);
    Wx1[idx] = h; Wx1[122880 + idx] = l;
  }
  if (idx < 409600) {   // We [2][640][640]: row 2u = (Wr,Wi), 2u+1 = (Wi,-Wr)
    int j2 = idx / 640, k = idx % 640;
    int u = j2 >> 1, pc = j2 & 1;
    int mm = k >> 1, p = k & 1;
    float val = 0.f;
    if (u < 298 && mm < 298) {
      int m = (u * mm) % 298;
      float ph = (TWO_PI / 298.0f) * (float)m;
      float sn, cs; sincosf(ph, &sn, &cs);
      val = (pc == 0) ? (p == 0 ? cs : -sn) : (p == 0 ? -sn : -cs);
    }
    u16 h, l; split2(val, h, l);
    We[idx] = h; We[409600 + idx] = l;
  }
  if (idx < 40960) {    // B4t [1][256][320]: k'=2v+p = fac*(re,im) of W[v][n+21]
    int v = idx / 256, n = idx % 256;
    float re = 0.f, im = 0.f;
    if (v < 150) {
      int m = (v * (n + 21)) % 298;
      float ang = (-TWO_PI / 298.0f) * (float)m;
      float s, c; sincosf(ang, &s, &c);
      float fac = (v >= 1 && v < 149) ? 2.f : 1.f;
      re = fac * c; im = fac * s;
    }
    size_t o = (size_t)n * 320 + 2 * v;
    B4t[o] = f2h(re); B4t[o + 1] = f2h(im);
  }
}

// ---------- 1x1 reduce conv ----------
__global__ __launch_bounds__(256) void reduce_k(const float* __restrict__ x,
                                                const float* __restrict__ w,
                                                const float* __restrict__ bias,
                                                float* __restrict__ cls) {
  __shared__ float ws_[1024];
  __shared__ float bs_[16];
  int t = threadIdx.x;
  for (int i = t; i < 1024; i += 256) ws_[i] = w[i];
  if (t < 16) bs_[t] = bias[t];
  __syncthreads();
  int b = blockIdx.y;
  int hw = blockIdx.x * 256 + t;
  const float* xb = x + ((size_t)b * 64) * 65536 + hw;
  float acc[16];
#pragma unroll
  for (int c = 0; c < 16; c++) acc[c] = bs_[c];
  for (int k = 0; k < 64; k++) {
    float xv = xb[(size_t)k * 65536];
#pragma unroll
    for (int c = 0; c < 16; c++) acc[c] = fmaf(ws_[c * 64 + k], xv, acc[c]);
  }
  float* ob = cls + ((size_t)b * 16) * 65536 + hw;
#pragma unroll
  for (int c = 0; c < 16; c++) ob[(size_t)c * 65536] = acc[c];
}

// ---------- 3x3 VALID conv ----------
__global__ __launch_bounds__(256) void conv3_k(const float* __restrict__ in,
                                               const float* __restrict__ w,
                                               const float* __restrict__ bias,
                                               float* __restrict__ out,
                                               int HI, int WI, int relu) {
  __shared__ float ws_[2304];
  __shared__ float bs_[16];
  int t = threadIdx.x;
  for (int i = t; i < 2304; i += 256) ws_[i] = w[i];
  if (t < 16) bs_[t] = bias[t];
  __syncthreads();
  int HO = HI - 2, WO = WI - 2;
  int b = blockIdx.y;
  int idx = blockIdx.x * 256 + t;
  if (idx >= HO * WO) return;
  int y = idx / WO, xx = idx % WO;
  const float* ib = in + ((size_t)b * 16) * (size_t)(HI * WI);
  float acc[16];
#pragma unroll
  for (int c = 0; c < 16; c++) acc[c] = bs_[c];
  for (int ci = 0; ci < 16; ci++) {
    const float* p = ib + (size_t)ci * (HI * WI) + (size_t)y * WI + xx;
#pragma unroll
    for (int dy = 0; dy < 3; dy++) {
#pragma unroll
      for (int dx = 0; dx < 3; dx++) {
        float v = p[dy * WI + dx];
        int widx = ci * 9 + dy * 3 + dx;
#pragma unroll
        for (int co = 0; co < 16; co++)
          acc[co] = fmaf(ws_[co * 144 + widx], v, acc[co]);
      }
    }
  }
  float* ob = out + ((size_t)b * 16) * (size_t)(HO * WO) + (size_t)y * WO + xx;
#pragma unroll
  for (int co = 0; co < 16; co++) {
    float v = acc[co];
    if (relu) v = v > 0.f ? v : 0.1f * v;
    ob[(size_t)co * (HO * WO)] = v;
  }
}

// ---------- adaptive avg pool 250x250 -> 3x3 ----------
__global__ __launch_bounds__(256) void pool_k(const float* __restrict__ g,
                                              float* __restrict__ poolo) {
  int blk = blockIdx.x;
  int bc = blk / 9;
  int ij = blk % 9;
  int i = ij / 3, j = ij % 3;
  const int r0s[3] = {0, 83, 166}, r1s[3] = {84, 167, 250};
  int r0 = r0s[i], r1 = r1s[i], c0 = r0s[j], c1 = r1s[j];
  const float* p = g + (size_t)bc * 62500;
  int nc = c1 - c0;
  int tot = (r1 - r0) * nc;
  float s = 0.f;
  for (int e = threadIdx.x; e < tot; e += 256) {
    int rr = e / nc, cc = e % nc;
    s += p[(r0 + rr) * 250 + c0 + cc];
  }
  for (int off = 32; off > 0; off >>= 1) s += __shfl_down(s, off, 64);
  __shared__ float red[4];
  int lane = threadIdx.x & 63, wid = threadIdx.x >> 6;
  if (lane == 0) red[wid] = s;
  __syncthreads();
  if (threadIdx.x == 0) poolo[blk] = (red[0] + red[1] + red[2] + red[3]) / (float)tot;
}

// ---------- kernel_P ----------
__global__ __launch_bounds__(256) void kp_k(const float* __restrict__ poolv,
                                            const float* __restrict__ w4,
                                            const float* __restrict__ b4,
                                            float* __restrict__ kp) {
  int b = blockIdx.x;
  int t = threadIdx.x;
  __shared__ float vals[144];
  __shared__ float w_[256];
  __shared__ float bb[16];
  if (t < 256) w_[t] = w4[t];
  if (t < 16) bb[t] = b4[t];
  __syncthreads();
  if (t < 144) {
    int c = t / 9, ij = t % 9;
    float a = bb[c];
    for (int k = 0; k < 16; k++)
      a = fmaf(w_[c * 16 + k], poolv[b * 144 + k * 9 + ij], a);
    vals[t] = expf(a);
  }
  __syncthreads();
  if (t < 144) {
    int c = t / 9;
    float m = 0.f;
#pragma unroll
    for (int q = 0; q < 9; q++) m += vals[c * 9 + q];
    kp[b * 144 + t] = vals[t] - m * (1.0f / 9.0f);
  }
}

// ---------- pad (edge) + split2 into [2][64][384][320] fp16 ----------
__global__ __launch_bounds__(256) void padsplit_k(const float* __restrict__ cls,
                                                  u16* __restrict__ p0) {
  size_t idx = (size_t)blockIdx.x * 256 + threadIdx.x;
  if (idx >= 7864320u) return;
  int n = (int)(idx % 320);
  size_t rest = idx / 320;
  int m = (int)(rest % 384);
  size_t img = rest / 384;
  float val = 0.f;
  if (m < 298 && n < 298) {
    int sy = min(max(m - 21, 0), 255);
    int sx = min(max(n - 21, 0), 255);
    val = cls[img * 65536 + (size_t)sy * 256 + sx];
  }
  u16 h, l; split2(val, h, l);
  p0[idx] = h;
  p0[7864320u + idx] = l;
}

// ---------- Kf (half-plane v<150) ----------
__global__ __launch_bounds__(256) void kf_k(const float* __restrict__ ker,
                                            const float2* __restrict__ tw,
                                            float2* __restrict__ Kf) {
  int b = blockIdx.y;
  __shared__ float ks[441];
  int t = threadIdx.x;
  for (int i = t; i < 441; i += 256) ks[i] = ker[b * 441 + i];
  __syncthreads();
  int uv = blockIdx.x * 256 + t;
  if (uv >= 298 * 150) return;
  int u = uv / 150, v = uv % 150;
  int tu = (10 * u) % 298, tv = (10 * v) % 298;
  int t_i = (2 * 298 - tu - tv) % 298;
  float ar = 0.f, ai = 0.f;
  for (int i = 0; i < 21; i++) {
    int tt = t_i;
#pragma unroll
    for (int j = 0; j < 21; j++) {
      float kv = ks[i * 21 + j];
      float2 wv = tw[tt];
      ar = fmaf(kv, wv.x, ar);
      ai = fmaf(kv, wv.y, ai);
      tt += v; if (tt >= 298) tt -= 298;
    }
    t_i += u; if (t_i >= 298) t_i -= 298;
  }
  Kf[(size_t)b * (298 * 150) + uv] = make_float2(ar, ai);
}

// ---------- Wiener on Gt[v][u] fp32 -> Ge [1][64][384][640] fp16 expanded ----
// Single plane: post-division path tolerates fp16 relative error.
__global__ __launch_bounds__(256) void gmul_k(const float* __restrict__ Gt,
                                              const float2* __restrict__ Kf,
                                              const float* __restrict__ kp,
                                              const float2* __restrict__ tw,
                                              u32* __restrict__ Geu) {
  int img = blockIdx.y;
  int b = img >> 4;
  __shared__ float kps[9];
  if (threadIdx.x < 9) kps[threadIdx.x] = kp[img * 9 + threadIdx.x];
  __syncthreads();
  int idx = blockIdx.x * 256 + threadIdx.x;
  if (idx >= 192 * 320) return;
  int u = idx % 320, v = idx / 320;
  float gr = 0.f, gi = 0.f;
  if (v < 150 && u < 298) {
    const float* gp = Gt + (size_t)img * 102400 + (size_t)v * 640 + 2 * u;
    float fr = gp[0], fi = gp[1];
    int um = (u == 0) ? 0 : (298 - u);
    int vm = (v == 0) ? 0 : (298 - v);
    int iu[3] = {um, 0, u}, jv[3] = {vm, 0, v};
    float pr = 0.f, pi = 0.f;
#pragma unroll
    for (int i = 0; i < 3; i++) {
#pragma unroll
      for (int j = 0; j < 3; j++) {
        int tt = iu[i] + jv[j];
        if (tt >= 298) tt -= 298;
        float kv = kps[i * 3 + j];
        float2 wv = tw[tt];
        pr = fmaf(kv, wv.x, pr);
        pi = fmaf(kv, wv.y, pi);
      }
    }
    float2 kf = Kf[(size_t)b * 44700 + (size_t)u * 150 + v];
    float denom = kf.x * kf.x + kf.y * kf.y + pr * pr + pi * pi;
    float inv = 1.0f / denom;
    float ir = kf.x * inv, ii = -kf.y * inv;
    gr = (ir * fr - ii * fi) * S_GMUL;
    gi = (ir * fi + ii * fr) * S_GMUL;
  }
  u16 ghr = f2h(gr), ghi = f2h(gi);
  size_t base = (size_t)img * 122880 + (size_t)(2 * v) * 320 + u;
  Geu[base]       = (u32)ghr | ((u32)ghi << 16);               // row 2v: ( r,  i)
  Geu[base + 320] = (u32)ghi | ((u32)(ghr ^ 0x8000u) << 16);   // row 2v+1: ( i, -r)
}

// ---------- unified fp16-split MFMA GEMM ----------
// BM=BN=128, BK=32, 4 waves (2x2), wave tile 64x64, 16x16x32 f16 frags.
// V=1,2: 2 planes, 3 MFMA products (fp32-emulating). V=3,4: 1 plane, 1 product.
#define LPITCH 40
#define ALSZ (128 * LPITCH)

template <int V>
__global__ __launch_bounds__(256, 3) void gemmF(
    const u16* __restrict__ Asrc, const u16* __restrict__ Bsrc,
    float* __restrict__ oF, u16* __restrict__ o0, int KT) {
  constexpr int PL = (V <= 2) ? 2 : 1;
  __shared__ u16 lds[PL * 2 * ALSZ];
  u16* Al = lds;
  u16* Bl = lds + PL * ALSZ;
  const int tid = threadIdx.x;
  const int img = blockIdx.z;
  const int m0 = blockIdx.y * 128;
  const int n0 = blockIdx.x * 128;
  const int lane = tid & 63;
  const int w = tid >> 6;
  const int wm = w & 1, wn = w >> 1;

  f32x4 acc[4][4];
#pragma unroll
  for (int i = 0; i < 4; i++)
#pragma unroll
    for (int j = 0; j < 4; j++) acc[i][j] = (f32x4){0.f, 0.f, 0.f, 0.f};

  for (int kt = 0; kt < KT; ++kt) {
    // ---- stage A: PL planes x 128 rows x 32 f16 ----
#pragma unroll
    for (int s = 0; s < 2 * PL; ++s) {
      int c = tid + s * 256;
      int p = c >> 9, rem = c & 511;
      int r = rem >> 2, q = rem & 3;
      uint4 val = make_uint4(0u, 0u, 0u, 0u);
      if constexpr (V == 1) {
        val = *(const uint4*)(Asrc + (size_t)p * 122880u + (size_t)(m0 + r) * 320 + kt * 32 + q * 8);
      } else if constexpr (V == 2) {
        int gr = m0 + r;
        if (gr < 192)
          val = *(const uint4*)(Asrc + (size_t)p * 7864320u + (size_t)img * 122880u +
                                (size_t)gr * 640 + kt * 32 + q * 8);
      } else if constexpr (V == 3) {
        val = *(const uint4*)(Asrc + (size_t)(2 * (m0 + r + 21)) * 640 + kt * 32 + q * 8);
      } else {
        val = *(const uint4*)(Asrc + (size_t)img * 81920u + (size_t)(m0 + r) * 320 + kt * 32 + q * 8);
      }
      *(uint4*)&Al[p * ALSZ + r * LPITCH + q * 8] = val;
    }
    // ---- stage B^T: PL planes x 128 rows x 32 f16 ----
#pragma unroll
    for (int s = 0; s < 2 * PL; ++s) {
      int c = tid + s * 256;
      int p = c >> 9, rem = c & 511;
      int rr = rem >> 2, q = rem & 3;
      uint4 val;
      if constexpr (V == 1) {
        val = *(const uint4*)(Bsrc + (size_t)p * 7864320u + (size_t)img * 122880u +
                              (size_t)(n0 + rr) * 320 + kt * 32 + q * 8);
      } else if constexpr (V == 2) {
        val = *(const uint4*)(Bsrc + (size_t)p * 409600u + (size_t)(n0 + rr) * 640 + kt * 32 + q * 8);
      } else if constexpr (V == 3) {
        val = *(const uint4*)(Bsrc + (size_t)img * 245760u + (size_t)(n0 + rr) * 640 + kt * 32 + q * 8);
      } else {
        val = *(const uint4*)(Bsrc + (size_t)(n0 + rr) * 320 + kt * 32 + q * 8);
      }
      *(uint4*)&Bl[p * ALSZ + rr * LPITCH + q * 8] = val;
    }
    __syncthreads();

    // ---- fragments ----
    f16x8 af[4][PL], bf[4][PL];
    const int arow = wm * 64 + (lane & 15);
    const int brow = wn * 64 + (lane & 15);
    const int c8 = (lane >> 4) * 8;
#pragma unroll
    for (int fm = 0; fm < 4; ++fm)
#pragma unroll
      for (int p = 0; p < PL; ++p)
        af[fm][p] = *(const f16x8*)&Al[p * ALSZ + (arow + fm * 16) * LPITCH + c8];
#pragma unroll
    for (int fn = 0; fn < 4; ++fn)
#pragma unroll
      for (int p = 0; p < PL; ++p)
        bf[fn][p] = *(const f16x8*)&Bl[p * ALSZ + (brow + fn * 16) * LPITCH + c8];
#pragma unroll
    for (int fm = 0; fm < 4; ++fm)
#pragma unroll
      for (int fn = 0; fn < 4; ++fn) {
        f32x4 a = acc[fm][fn];
        if constexpr (PL == 2) {
          a = __builtin_amdgcn_mfma_f32_16x16x32_f16(af[fm][1], bf[fn][0], a, 0, 0, 0);
          a = __builtin_amdgcn_mfma_f32_16x16x32_f16(af[fm][0], bf[fn][1], a, 0, 0, 0);
          a = __builtin_amdgcn_mfma_f32_16x16x32_f16(af[fm][0], bf[fn][0], a, 0, 0, 0);
        } else {
          a = __builtin_amdgcn_mfma_f32_16x16x32_f16(af[fm][0], bf[fn][0], a, 0, 0, 0);
        }
        acc[fm][fn] = a;
      }
    __syncthreads();
  }

  // ---- epilogue ----
  const int rowL = (lane >> 4) * 4;
  const int colL = lane & 15;
#pragma unroll
  for (int fm = 0; fm < 4; ++fm)
#pragma unroll
    for (int fn = 0; fn < 4; ++fn) {
      int gcol = n0 + wn * 64 + fn * 16 + colL;
      int rbase = m0 + wm * 64 + fm * 16 + rowL;
      if constexpr (V == 1) {
        // rows rho -> T1e[v=rho>>1][2*mcol + (rho&1)], u32-paired, 2 planes
        if (gcol < 320) {
          u32* T1u = (u32*)o0;
#pragma unroll
          for (int i = 0; i < 4; i += 2) {
            int rho = rbase + i;
            int v = rho >> 1;
            u16 h0, l0, h1, l1;
            split2(acc[fm][fn][i], h0, l0);
            split2(acc[fm][fn][i + 1], h1, l1);
            size_t off = (size_t)img * 61440u + (size_t)v * 320 + gcol;
            T1u[off] = (u32)h0 | ((u32)h1 << 16);
            T1u[3932160u + off] = (u32)l0 | ((u32)l1 << 16);
          }
        }
      } else if constexpr (V == 2) {
#pragma unroll
        for (int i = 0; i < 4; ++i) {
          int vg = rbase + i;
          if (vg < 160)
            oF[(size_t)img * 102400u + (size_t)vg * 640 + gcol] = acc[fm][fn][i];
        }
      } else if constexpr (V == 3) {
        if (gcol < 320) {
#pragma unroll
          for (int i = 0; i < 4; ++i) {
            int mg = rbase + i;
            size_t off = (size_t)img * 81920u + (size_t)mg * 320 + gcol;
            o0[off] = f2h(acc[fm][fn][i] * S_P3);
          }
        }
      } else {
#pragma unroll
        for (int i = 0; i < 4; ++i) {
          int mg = rbase + i;
          oF[(size_t)img * 65536u + (size_t)mg * 256 + gcol] = acc[fm][fn][i] * S_P4;
        }
      }
    }
}

// ---------- 1x1 expand conv ----------
__global__ __launch_bounds__(256) void expand_k(const float* __restrict__ D,
                                                const float* __restrict__ w,
                                                const float* __restrict__ bias,
                                                float* __restrict__ out) {
  __shared__ float ws_[1024];
  __shared__ float bs_[64];
  int t = threadIdx.x;
  for (int i = t; i < 1024; i += 256) ws_[i] = w[i];
  if (t < 64) bs_[t] = bias[t];
  __syncthreads();
  int b = blockIdx.y;
  int hw = blockIdx.x * 256 + t;
  const float* Db = D + (size_t)b * 16 * DSLAB + hw;
  float d[16];
#pragma unroll
  for (int c = 0; c < 16; c++) d[c] = Db[(size_t)c * DSLAB];
  float* ob = out + ((size_t)b * 64) * 65536 + hw;
  for (int o = 0; o < 64; o++) {
    float a = bs_[o];
#pragma unroll
    for (int c = 0; c < 16; c++) a = fmaf(ws_[o * 16 + c], d[c], a);
    ob[(size_t)o * 65536] = a;
  }
}

extern "C" void kernel_launch(void* const* d_in, const int* in_sizes, int n_in,
                              void* d_out, int out_size, void* d_ws, size_t ws_size,
                              hipStream_t stream) {
  (void)in_sizes; (void)n_in; (void)out_size; (void)ws_size;
  const float* x        = (const float*)d_in[0];
  const float* kernel   = (const float*)d_in[1];
  const float* w_reduce = (const float*)d_in[2];
  const float* b_reduce = (const float*)d_in[3];
  const float* w_g1     = (const float*)d_in[4];
  const float* b_g1     = (const float*)d_in[5];
  const float* w_g2     = (const float*)d_in[6];
  const float* b_g2     = (const float*)d_in[7];
  const float* w_g3     = (const float*)d_in[8];
  const float* b_g3     = (const float*)d_in[9];
  const float* w_g4     = (const float*)d_in[10];
  const float* b_g4     = (const float*)d_in[11];
  const float* w_expand = (const float*)d_in[12];
  const float* b_expand = (const float*)d_in[13];
  float* out = (float*)d_out;

  // ---- workspace layout (float offsets); all aliases time-disjoint ----
  float* ws_f = (float*)d_ws;
  float* cls   = ws_f;
  float* gA    = ws_f + 4194304;
  float* gB    = ws_f + 8323328;
  u16*  padsp  = (u16*)(ws_f + 4194304);
  u16*  T1e    = (u16*)(ws_f + 12452352);
  float* Gt    = ws_f;
  u16*  Ge     = (u16*)(ws_f + 12452352);     // single plane now: 7.86M f
  u16*  E2     = (u16*)ws_f;                  // single plane: 2.62M f
  float* Df    = ws_f + 5242880;
  float2* tw   = (float2*)(ws_f + 28180992);
  float2* Kf2  = (float2*)(ws_f + 28182016);
  u16*  Wx1    = (u16*)(ws_f + 28540416);
  u16*  We     = (u16*)(ws_f + 28663296);
  u16*  B4t    = (u16*)(ws_f + 29072896);
  float* poolb = ws_f + 29154816;
  float* kpb   = ws_f + 29155392;

  // ---- static tables (single fused launch) ----
  tables_k<<<dim3(1600), 256, 0, stream>>>(tw, Wx1, We, B4t);

  // ---- conv chain ----
  reduce_k<<<dim3(256, NB), 256, 0, stream>>>(x, w_reduce, b_reduce, cls);
  conv3_k<<<dim3((254 * 254 + 255) / 256, NB), 256, 0, stream>>>(cls, w_g1, b_g1, gA, 256, 256, 1);
  conv3_k<<<dim3((252 * 252 + 255) / 256, NB), 256, 0, stream>>>(gA, w_g2, b_g2, gB, 254, 254, 1);
  conv3_k<<<dim3((250 * 250 + 255) / 256, NB), 256, 0, stream>>>(gB, w_g3, b_g3, gA, 252, 252, 0);
  pool_k<<<dim3(NB * 16 * 9), 256, 0, stream>>>(gA, poolb);
  kp_k<<<dim3(NB), 256, 0, stream>>>(poolb, w_g4, b_g4, kpb);

  // ---- pad + split, Kf ----
  padsplit_k<<<dim3(30720), 256, 0, stream>>>(cls, padsp);
  kf_k<<<dim3((298 * 150 + 255) / 256, NB), 256, 0, stream>>>(kernel, tw, Kf2);

  // ---- P1: T1e[v][2m+s] = Wx1 x pad^T  (2-plane, 3-product) ----
  gemmF<1><<<dim3(3, 3, IMGS), 256, 0, stream>>>(Wx1, padsp, nullptr, T1e, 10);
  // ---- P2: Gt[v][2u+pc] = T1e x We^T  (2-plane, 3-product) ----
  gemmF<2><<<dim3(5, 2, IMGS), 256, 0, stream>>>(T1e, We, Gt, nullptr, 20);
  // ---- Wiener + expand -> Ge (single plane, scaled 1/64) ----
  gmul_k<<<dim3(240, IMGS), 256, 0, stream>>>(Gt, Kf2, kpb, tw, (u32*)Ge);
  // ---- P3: E[m][2v+q] = We(rows 2(m+21)) x Ge^T  (1-plane, 1-product) ----
  gemmF<3><<<dim3(3, 2, IMGS), 256, 0, stream>>>(We, Ge, nullptr, E2, 20);
  // ---- P4: D = E2 x B4t^T * 65536/88804  (1-plane, 1-product) ----
  gemmF<4><<<dim3(2, 2, IMGS), 256, 0, stream>>>(E2, B4t, Df, nullptr, 10);
  // ---- expand ----
  expand_k<<<dim3(256, NB), 256, 0, stream>>>(Df, w_expand, b_expand, out);
}

// Round 9
// 377.096 us; speedup vs baseline: 2.8494x; 1.0233x over previous
//
#include <hip/hip_runtime.h>
#include <math.h>

typedef unsigned short u16;
typedef unsigned int   u32;
typedef _Float16 f16x8 __attribute__((ext_vector_type(8)));
typedef __attribute__((ext_vector_type(4))) float f32x4;

#define NB    4
#define IMGS  64
#define DSLAB (256*256)
#define TWO_PI 6.283185307179586f

// Scale plan (pipeline linear in pad; total compensated exactly in P4):
#define S_WX1  0.015625f
#define S_GMUL 0.015625f
#define S_P3   0.0625f
#define S_P4   (65536.0f / 88804.0f)

// ---------- fp16 2-way split ----------
__device__ __forceinline__ void split2(float x, u16& h, u16& l) {
  _Float16 hh = (_Float16)x;
  float r = x - (float)hh;
  _Float16 ll = (_Float16)r;
  h = *(u16*)&hh; l = *(u16*)&ll;
}
__device__ __forceinline__ u16 f2h(float x) {
  _Float16 hh = (_Float16)x;
  return *(u16*)&hh;
}

// ---------- async global->LDS 16B DMA ----------
__device__ __forceinline__ void gload16(const u16* g, u16* l) {
  __builtin_amdgcn_global_load_lds(
      (__attribute__((address_space(1))) void*)(g),
      (__attribute__((address_space(3))) void*)(l),
      16, 0, 0);
}

// ---------- fused static tables: tw, Wx1, We, B4t in ONE launch ----------
__global__ __launch_bounds__(256) void tables_k(float2* __restrict__ tw,
                                                u16* __restrict__ Wx1,
                                                u16* __restrict__ We,
                                                u16* __restrict__ B4t) {
  int idx = blockIdx.x * 256 + threadIdx.x;
  if (idx < 298) {
    float ang = (-TWO_PI / 298.0f) * (float)idx;
    float s, c; sincosf(ang, &s, &c);
    tw[idx] = make_float2(c, s);
  }
  if (idx < 122880) {   // Wx1 [2][384][320]
    int rho = idx / 320, n = idx % 320;
    float val = 0.f;
    if (rho < 300 && n < 298) {
      int v = rho >> 1, s = rho & 1;
      int m = (v * n) % 298;
      float ph = (TWO_PI / 298.0f) * (float)m;
      float sn, cs; sincosf(ph, &sn, &cs);
      val = (s ? sn : cs) * S_WX1;
    }
    u16 h, l; split2(val, h, l);
    Wx1[idx] = h; Wx1[122880 + idx] = l;
  }
  if (idx < 409600) {   // We [2][640][640]
    int j2 = idx / 640, k = idx % 640;
    int u = j2 >> 1, pc = j2 & 1;
    int mm = k >> 1, p = k & 1;
    float val = 0.f;
    if (u < 298 && mm < 298) {
      int m = (u * mm) % 298;
      float ph = (TWO_PI / 298.0f) * (float)m;
      float sn, cs; sincosf(ph, &sn, &cs);
      val = (pc == 0) ? (p == 0 ? cs : -sn) : (p == 0 ? -sn : -cs);
    }
    u16 h, l; split2(val, h, l);
    We[idx] = h; We[409600 + idx] = l;
  }
  if (idx < 40960) {    // B4t [1][256][320]
    int v = idx / 256, n = idx % 256;
    float re = 0.f, im = 0.f;
    if (v < 150) {
      int m = (v * (n + 21)) % 298;
      float ang = (-TWO_PI / 298.0f) * (float)m;
      float s, c; sincosf(ang, &s, &c);
      float fac = (v >= 1 && v < 149) ? 2.f : 1.f;
      re = fac * c; im = fac * s;
    }
    size_t o = (size_t)n * 320 + 2 * v;
    B4t[o] = f2h(re); B4t[o + 1] = f2h(im);
  }
}

// ---------- 1x1 reduce conv ----------
__global__ __launch_bounds__(256) void reduce_k(const float* __restrict__ x,
                                                const float* __restrict__ w,
                                                const float* __restrict__ bias,
                                                float* __restrict__ cls) {
  __shared__ float ws_[1024];
  __shared__ float bs_[16];
  int t = threadIdx.x;
  for (int i = t; i < 1024; i += 256) ws_[i] = w[i];
  if (t < 16) bs_[t] = bias[t];
  __syncthreads();
  int b = blockIdx.y;
  int hw = blockIdx.x * 256 + t;
  const float* xb = x + ((size_t)b * 64) * 65536 + hw;
  float acc[16];
#pragma unroll
  for (int c = 0; c < 16; c++) acc[c] = bs_[c];
  for (int k = 0; k < 64; k++) {
    float xv = xb[(size_t)k * 65536];
#pragma unroll
    for (int c = 0; c < 16; c++) acc[c] = fmaf(ws_[c * 64 + k], xv, acc[c]);
  }
  float* ob = cls + ((size_t)b * 16) * 65536 + hw;
#pragma unroll
  for (int c = 0; c < 16; c++) ob[(size_t)c * 65536] = acc[c];
}

// ---------- 3x3 VALID conv ----------
__global__ __launch_bounds__(256) void conv3_k(const float* __restrict__ in,
                                               const float* __restrict__ w,
                                               const float* __restrict__ bias,
                                               float* __restrict__ out,
                                               int HI, int WI, int relu) {
  __shared__ float ws_[2304];
  __shared__ float bs_[16];
  int t = threadIdx.x;
  for (int i = t; i < 2304; i += 256) ws_[i] = w[i];
  if (t < 16) bs_[t] = bias[t];
  __syncthreads();
  int HO = HI - 2, WO = WI - 2;
  int b = blockIdx.y;
  int idx = blockIdx.x * 256 + t;
  if (idx >= HO * WO) return;
  int y = idx / WO, xx = idx % WO;
  const float* ib = in + ((size_t)b * 16) * (size_t)(HI * WI);
  float acc[16];
#pragma unroll
  for (int c = 0; c < 16; c++) acc[c] = bs_[c];
  for (int ci = 0; ci < 16; ci++) {
    const float* p = ib + (size_t)ci * (HI * WI) + (size_t)y * WI + xx;
#pragma unroll
    for (int dy = 0; dy < 3; dy++) {
#pragma unroll
      for (int dx = 0; dx < 3; dx++) {
        float v = p[dy * WI + dx];
        int widx = ci * 9 + dy * 3 + dx;
#pragma unroll
        for (int co = 0; co < 16; co++)
          acc[co] = fmaf(ws_[co * 144 + widx], v, acc[co]);
      }
    }
  }
  float* ob = out + ((size_t)b * 16) * (size_t)(HO * WO) + (size_t)y * WO + xx;
#pragma unroll
  for (int co = 0; co < 16; co++) {
    float v = acc[co];
    if (relu) v = v > 0.f ? v : 0.1f * v;
    ob[(size_t)co * (HO * WO)] = v;
  }
}

// ---------- adaptive avg pool 250x250 -> 3x3 ----------
__global__ __launch_bounds__(256) void pool_k(const float* __restrict__ g,
                                              float* __restrict__ poolo) {
  int blk = blockIdx.x;
  int bc = blk / 9;
  int ij = blk % 9;
  int i = ij / 3, j = ij % 3;
  const int r0s[3] = {0, 83, 166}, r1s[3] = {84, 167, 250};
  int r0 = r0s[i], r1 = r1s[i], c0 = r0s[j], c1 = r1s[j];
  const float* p = g + (size_t)bc * 62500;
  int nc = c1 - c0;
  int tot = (r1 - r0) * nc;
  float s = 0.f;
  for (int e = threadIdx.x; e < tot; e += 256) {
    int rr = e / nc, cc = e % nc;
    s += p[(r0 + rr) * 250 + c0 + cc];
  }
  for (int off = 32; off > 0; off >>= 1) s += __shfl_down(s, off, 64);
  __shared__ float red[4];
  int lane = threadIdx.x & 63, wid = threadIdx.x >> 6;
  if (lane == 0) red[wid] = s;
  __syncthreads();
  if (threadIdx.x == 0) poolo[blk] = (red[0] + red[1] + red[2] + red[3]) / (float)tot;
}

// ---------- kernel_P ----------
__global__ __launch_bounds__(256) void kp_k(const float* __restrict__ poolv,
                                            const float* __restrict__ w4,
                                            const float* __restrict__ b4,
                                            float* __restrict__ kp) {
  int b = blockIdx.x;
  int t = threadIdx.x;
  __shared__ float vals[144];
  __shared__ float w_[256];
  __shared__ float bb[16];
  if (t < 256) w_[t] = w4[t];
  if (t < 16) bb[t] = b4[t];
  __syncthreads();
  if (t < 144) {
    int c = t / 9, ij = t % 9;
    float a = bb[c];
    for (int k = 0; k < 16; k++)
      a = fmaf(w_[c * 16 + k], poolv[b * 144 + k * 9 + ij], a);
    vals[t] = expf(a);
  }
  __syncthreads();
  if (t < 144) {
    int c = t / 9;
    float m = 0.f;
#pragma unroll
    for (int q = 0; q < 9; q++) m += vals[c * 9 + q];
    kp[b * 144 + t] = vals[t] - m * (1.0f / 9.0f);
  }
}

// ---------- pad (edge) + split2 into [2][64][384][320] fp16 ----------
__global__ __launch_bounds__(256) void padsplit_k(const float* __restrict__ cls,
                                                  u16* __restrict__ p0) {
  size_t idx = (size_t)blockIdx.x * 256 + threadIdx.x;
  if (idx >= 7864320u) return;
  int n = (int)(idx % 320);
  size_t rest = idx / 320;
  int m = (int)(rest % 384);
  size_t img = rest / 384;
  float val = 0.f;
  if (m < 298 && n < 298) {
    int sy = min(max(m - 21, 0), 255);
    int sx = min(max(n - 21, 0), 255);
    val = cls[img * 65536 + (size_t)sy * 256 + sx];
  }
  u16 h, l; split2(val, h, l);
  p0[idx] = h;
  p0[7864320u + idx] = l;
}

// ---------- Kf (half-plane v<150) ----------
__global__ __launch_bounds__(256) void kf_k(const float* __restrict__ ker,
                                            const float2* __restrict__ tw,
                                            float2* __restrict__ Kf) {
  int b = blockIdx.y;
  __shared__ float ks[441];
  int t = threadIdx.x;
  for (int i = t; i < 441; i += 256) ks[i] = ker[b * 441 + i];
  __syncthreads();
  int uv = blockIdx.x * 256 + t;
  if (uv >= 298 * 150) return;
  int u = uv / 150, v = uv % 150;
  int tu = (10 * u) % 298, tv = (10 * v) % 298;
  int t_i = (2 * 298 - tu - tv) % 298;
  float ar = 0.f, ai = 0.f;
  for (int i = 0; i < 21; i++) {
    int tt = t_i;
#pragma unroll
    for (int j = 0; j < 21; j++) {
      float kv = ks[i * 21 + j];
      float2 wv = tw[tt];
      ar = fmaf(kv, wv.x, ar);
      ai = fmaf(kv, wv.y, ai);
      tt += v; if (tt >= 298) tt -= 298;
    }
    t_i += u; if (t_i >= 298) t_i -= 298;
  }
  Kf[(size_t)b * (298 * 150) + uv] = make_float2(ar, ai);
}

// ---------- Wiener on Gt[v][u] fp32 -> Ge [1][64][384][640] fp16 expanded ----
__global__ __launch_bounds__(256) void gmul_k(const float* __restrict__ Gt,
                                              const float2* __restrict__ Kf,
                                              const float* __restrict__ kp,
                                              const float2* __restrict__ tw,
                                              u32* __restrict__ Geu) {
  int img = blockIdx.y;
  int b = img >> 4;
  __shared__ float kps[9];
  if (threadIdx.x < 9) kps[threadIdx.x] = kp[img * 9 + threadIdx.x];
  __syncthreads();
  int idx = blockIdx.x * 256 + threadIdx.x;
  if (idx >= 192 * 320) return;
  int u = idx % 320, v = idx / 320;
  float gr = 0.f, gi = 0.f;
  if (v < 150 && u < 298) {
    const float* gp = Gt + (size_t)img * 102400 + (size_t)v * 640 + 2 * u;
    float fr = gp[0], fi = gp[1];
    int um = (u == 0) ? 0 : (298 - u);
    int vm = (v == 0) ? 0 : (298 - v);
    int iu[3] = {um, 0, u}, jv[3] = {vm, 0, v};
    float pr = 0.f, pi = 0.f;
#pragma unroll
    for (int i = 0; i < 3; i++) {
#pragma unroll
      for (int j = 0; j < 3; j++) {
        int tt = iu[i] + jv[j];
        if (tt >= 298) tt -= 298;
        float kv = kps[i * 3 + j];
        float2 wv = tw[tt];
        pr = fmaf(kv, wv.x, pr);
        pi = fmaf(kv, wv.y, pi);
      }
    }
    float2 kf = Kf[(size_t)b * 44700 + (size_t)u * 150 + v];
    float denom = kf.x * kf.x + kf.y * kf.y + pr * pr + pi * pi;
    float inv = 1.0f / denom;
    float ir = kf.x * inv, ii = -kf.y * inv;
    gr = (ir * fr - ii * fi) * S_GMUL;
    gi = (ir * fi + ii * fr) * S_GMUL;
  }
  u16 ghr = f2h(gr), ghi = f2h(gi);
  size_t base = (size_t)img * 122880 + (size_t)(2 * v) * 320 + u;
  Geu[base]       = (u32)ghr | ((u32)ghi << 16);               // row 2v: ( r,  i)
  Geu[base + 320] = (u32)ghi | ((u32)(ghr ^ 0x8000u) << 16);   // row 2v+1: ( i, -r)
}

// ---------- unified fp16-split MFMA GEMM, gload_lds + XOR-swizzled LDS ------
// BM=BN=128, BK=64 (128B rows), 4 waves (2x2), wave tile 64x64.
// LDS tile: [PL][128 rows][64 u16], linear; slot s (16B) holds global chunk
// s ^ (row&7) (pre-swizzled global source); reads XOR the same way -> 2-way.
template <int V>
__global__ __launch_bounds__(256) void gemmF(
    const u16* __restrict__ Asrc, const u16* __restrict__ Bsrc,
    float* __restrict__ oF, u16* __restrict__ o0, int KT) {
  constexpr int PL = (V <= 2) ? 2 : 1;
  __shared__ u16 lds[PL * 2 * 8192];
  u16* Al = lds;
  u16* Bl = lds + PL * 8192;
  const int tid = threadIdx.x;
  const int img = blockIdx.z;
  const int m0 = blockIdx.y * 128;
  const int n0 = blockIdx.x * 128;
  const int l = tid & 63;
  const int w = tid >> 6;
  const int wm = w & 1, wn = w >> 1;
  const int rof = l >> 3;              // row within 8-row block
  const int sub = (l & 7) ^ rof;       // pre-swizzled global 16B-chunk index
  const int arow = wm * 64 + (l & 15);
  const int brow = wn * 64 + (l & 15);

  f32x4 acc[4][4];
#pragma unroll
  for (int i = 0; i < 4; i++)
#pragma unroll
    for (int j = 0; j < 4; j++) acc[i][j] = (f32x4){0.f, 0.f, 0.f, 0.f};

  for (int kt = 0; kt < KT; ++kt) {
    const int kb = kt * 64;
    // ---- stage A: PL planes x 128 rows x 128B, 1KB per wave-issue ----
#pragma unroll
    for (int i = 0; i < PL * 4; ++i) {
      int q = w + i * 4;
      int p = (PL == 2) ? (q >> 4) : 0;
      int j = (PL == 2) ? (q & 15) : q;
      int r = j * 8 + rof;
      const u16* ga;
      if constexpr (V == 1) {
        ga = Asrc + (size_t)p * 122880u + (size_t)(m0 + r) * 320 + kb + sub * 8;
      } else if constexpr (V == 2) {
        int gr = m0 + r; if (gr > 191) gr = 191;
        ga = Asrc + (size_t)p * 7864320u + (size_t)img * 122880u +
             (size_t)gr * 640 + kb + sub * 8;
      } else if constexpr (V == 3) {
        ga = Asrc + (size_t)(2 * (m0 + r + 21)) * 640 + kb + sub * 8;
      } else {
        ga = Asrc + (size_t)img * 81920u + (size_t)(m0 + r) * 320 + kb + sub * 8;
      }
      gload16(ga, Al + q * 512);
    }
    // ---- stage B^T: PL planes x 128 rows x 128B ----
#pragma unroll
    for (int i = 0; i < PL * 4; ++i) {
      int q = w + i * 4;
      int p = (PL == 2) ? (q >> 4) : 0;
      int j = (PL == 2) ? (q & 15) : q;
      int rr = j * 8 + rof;
      const u16* gb;
      if constexpr (V == 1) {
        gb = Bsrc + (size_t)p * 7864320u + (size_t)img * 122880u +
             (size_t)(n0 + rr) * 320 + kb + sub * 8;
      } else if constexpr (V == 2) {
        gb = Bsrc + (size_t)p * 409600u + (size_t)(n0 + rr) * 640 + kb + sub * 8;
      } else if constexpr (V == 3) {
        gb = Bsrc + (size_t)img * 245760u + (size_t)(n0 + rr) * 640 + kb + sub * 8;
      } else {
        gb = Bsrc + (size_t)(n0 + rr) * 320 + kb + sub * 8;
      }
      gload16(gb, Bl + q * 512);
    }
    asm volatile("s_waitcnt vmcnt(0)" ::: "memory");
    __syncthreads();

    // ---- compute: 2 k-slices of 32 per BK=64 tile ----
#pragma unroll
    for (int kk = 0; kk < 2; ++kk) {
      const int slot = ((kk * 4 + (l >> 4)) ^ (l & 7)) * 8;
      f16x8 af[4][PL], bf[4][PL];
#pragma unroll
      for (int fm = 0; fm < 4; ++fm)
#pragma unroll
        for (int p = 0; p < PL; ++p)
          af[fm][p] = *(const f16x8*)&Al[p * 8192 + (arow + fm * 16) * 64 + slot];
#pragma unroll
      for (int fn = 0; fn < 4; ++fn)
#pragma unroll
        for (int p = 0; p < PL; ++p)
          bf[fn][p] = *(const f16x8*)&Bl[p * 8192 + (brow + fn * 16) * 64 + slot];
#pragma unroll
      for (int fm = 0; fm < 4; ++fm)
#pragma unroll
        for (int fn = 0; fn < 4; ++fn) {
          f32x4 a = acc[fm][fn];
          if constexpr (PL == 2) {
            a = __builtin_amdgcn_mfma_f32_16x16x32_f16(af[fm][1], bf[fn][0], a, 0, 0, 0);
            a = __builtin_amdgcn_mfma_f32_16x16x32_f16(af[fm][0], bf[fn][1], a, 0, 0, 0);
            a = __builtin_amdgcn_mfma_f32_16x16x32_f16(af[fm][0], bf[fn][0], a, 0, 0, 0);
          } else {
            a = __builtin_amdgcn_mfma_f32_16x16x32_f16(af[fm][0], bf[fn][0], a, 0, 0, 0);
          }
          acc[fm][fn] = a;
        }
    }
    __syncthreads();
  }

  // ---- epilogue ----
  const int rowL = (l >> 4) * 4;
  const int colL = l & 15;
#pragma unroll
  for (int fm = 0; fm < 4; ++fm)
#pragma unroll
    for (int fn = 0; fn < 4; ++fn) {
      int gcol = n0 + wn * 64 + fn * 16 + colL;
      int rbase = m0 + wm * 64 + fm * 16 + rowL;
      if constexpr (V == 1) {
        if (gcol < 320) {
          u32* T1u = (u32*)o0;
#pragma unroll
          for (int i = 0; i < 4; i += 2) {
            int rho = rbase + i;
            int v = rho >> 1;
            u16 h0, l0, h1, l1;
            split2(acc[fm][fn][i], h0, l0);
            split2(acc[fm][fn][i + 1], h1, l1);
            size_t off = (size_t)img * 61440u + (size_t)v * 320 + gcol;
            T1u[off] = (u32)h0 | ((u32)h1 << 16);
            T1u[3932160u + off] = (u32)l0 | ((u32)l1 << 16);
          }
        }
      } else if constexpr (V == 2) {
#pragma unroll
        for (int i = 0; i < 4; ++i) {
          int vg = rbase + i;
          if (vg < 160)
            oF[(size_t)img * 102400u + (size_t)vg * 640 + gcol] = acc[fm][fn][i];
        }
      } else if constexpr (V == 3) {
        if (gcol < 320) {
#pragma unroll
          for (int i = 0; i < 4; ++i) {
            int mg = rbase + i;
            size_t off = (size_t)img * 81920u + (size_t)mg * 320 + gcol;
            o0[off] = f2h(acc[fm][fn][i] * S_P3);
          }
        }
      } else {
#pragma unroll
        for (int i = 0; i < 4; ++i) {
          int mg = rbase + i;
          oF[(size_t)img * 65536u + (size_t)mg * 256 + gcol] = acc[fm][fn][i] * S_P4;
        }
      }
    }
}

// ---------- 1x1 expand conv ----------
__global__ __launch_bounds__(256) void expand_k(const float* __restrict__ D,
                                                const float* __restrict__ w,
                                                const float* __restrict__ bias,
                                                float* __restrict__ out) {
  __shared__ float ws_[1024];
  __shared__ float bs_[64];
  int t = threadIdx.x;
  for (int i = t; i < 1024; i += 256) ws_[i] = w[i];
  if (t < 64) bs_[t] = bias[t];
  __syncthreads();
  int b = blockIdx.y;
  int hw = blockIdx.x * 256 + t;
  const float* Db = D + (size_t)b * 16 * DSLAB + hw;
  float d[16];
#pragma unroll
  for (int c = 0; c < 16; c++) d[c] = Db[(size_t)c * DSLAB];
  float* ob = out + ((size_t)b * 64) * 65536 + hw;
  for (int o = 0; o < 64; o++) {
    float a = bs_[o];
#pragma unroll
    for (int c = 0; c < 16; c++) a = fmaf(ws_[o * 16 + c], d[c], a);
    ob[(size_t)o * 65536] = a;
  }
}

extern "C" void kernel_launch(void* const* d_in, const int* in_sizes, int n_in,
                              void* d_out, int out_size, void* d_ws, size_t ws_size,
                              hipStream_t stream) {
  (void)in_sizes; (void)n_in; (void)out_size; (void)ws_size;
  const float* x        = (const float*)d_in[0];
  const float* kernel   = (const float*)d_in[1];
  const float* w_reduce = (const float*)d_in[2];
  const float* b_reduce = (const float*)d_in[3];
  const float* w_g1     = (const float*)d_in[4];
  const float* b_g1     = (const float*)d_in[5];
  const float* w_g2     = (const float*)d_in[6];
  const float* b_g2     = (const float*)d_in[7];
  const float* w_g3     = (const float*)d_in[8];
  const float* b_g3     = (const float*)d_in[9];
  const float* w_g4     = (const float*)d_in[10];
  const float* b_g4     = (const float*)d_in[11];
  const float* w_expand = (const float*)d_in[12];
  const float* b_expand = (const float*)d_in[13];
  float* out = (float*)d_out;

  // ---- workspace layout (float offsets); all aliases time-disjoint ----
  float* ws_f = (float*)d_ws;
  float* cls   = ws_f;
  float* gA    = ws_f + 4194304;
  float* gB    = ws_f + 8323328;
  u16*  padsp  = (u16*)(ws_f + 4194304);
  u16*  T1e    = (u16*)(ws_f + 12452352);
  float* Gt    = ws_f;
  u16*  Ge     = (u16*)(ws_f + 12452352);
  u16*  E2     = (u16*)ws_f;
  float* Df    = ws_f + 5242880;
  float2* tw   = (float2*)(ws_f + 28180992);
  float2* Kf2  = (float2*)(ws_f + 28182016);
  u16*  Wx1    = (u16*)(ws_f + 28540416);
  u16*  We     = (u16*)(ws_f + 28663296);
  u16*  B4t    = (u16*)(ws_f + 29072896);
  float* poolb = ws_f + 29154816;
  float* kpb   = ws_f + 29155392;

  // ---- static tables (single fused launch) ----
  tables_k<<<dim3(1600), 256, 0, stream>>>(tw, Wx1, We, B4t);

  // ---- conv chain ----
  reduce_k<<<dim3(256, NB), 256, 0, stream>>>(x, w_reduce, b_reduce, cls);
  conv3_k<<<dim3((254 * 254 + 255) / 256, NB), 256, 0, stream>>>(cls, w_g1, b_g1, gA, 256, 256, 1);
  conv3_k<<<dim3((252 * 252 + 255) / 256, NB), 256, 0, stream>>>(gA, w_g2, b_g2, gB, 254, 254, 1);
  conv3_k<<<dim3((250 * 250 + 255) / 256, NB), 256, 0, stream>>>(gB, w_g3, b_g3, gA, 252, 252, 0);
  pool_k<<<dim3(NB * 16 * 9), 256, 0, stream>>>(gA, poolb);
  kp_k<<<dim3(NB), 256, 0, stream>>>(poolb, w_g4, b_g4, kpb);

  // ---- pad + split, Kf ----
  padsplit_k<<<dim3(30720), 256, 0, stream>>>(cls, padsp);
  kf_k<<<dim3((298 * 150 + 255) / 256, NB), 256, 0, stream>>>(kernel, tw, Kf2);

  // ---- P1: T1e = Wx1 x pad^T  (2-plane, 3-product, K=320 -> KT=5) ----
  gemmF<1><<<dim3(3, 3, IMGS), 256, 0, stream>>>(Wx1, padsp, nullptr, T1e, 5);
  // ---- P2: Gt = T1e x We^T  (2-plane, 3-product, K=640 -> KT=10) ----
  gemmF<2><<<dim3(5, 2, IMGS), 256, 0, stream>>>(T1e, We, Gt, nullptr, 10);
  // ---- Wiener + expand -> Ge (single plane, scaled 1/64) ----
  gmul_k<<<dim3(240, IMGS), 256, 0, stream>>>(Gt, Kf2, kpb, tw, (u32*)Ge);
  // ---- P3: E = We(rows 2(m+21)) x Ge^T  (1-plane, K=640 -> KT=10) ----
  gemmF<3><<<dim3(3, 2, IMGS), 256, 0, stream>>>(We, Ge, nullptr, E2, 10);
  // ---- P4: D = E2 x B4t^T  (1-plane, K=320 -> KT=5) ----
  gemmF<4><<<dim3(2, 2, IMGS), 256, 0, stream>>>(E2, B4t, Df, nullptr, 5);
  // ---- expand ----
  expand_k<<<dim3(256, NB), 256, 0, stream>>>(Df, w_expand, b_expand, out);
}